// Round 2
// baseline (896.207 us; speedup 1.0000x reference)
//
#include <hip/hip_runtime.h>

// ---- problem constants ----
#define NIN 64
#define NOPS 1024
#define NB 2048
#define NE 64
#define NNODES 1088            // NIN + NOPS

// ---- workspace layout (bytes) ----
#define WS_SCHED 0u            // u64[1024]
#define WS_LEV   8192u         // u32[1032]: [0]=nlev, [l]=start of level l, [nlev+1]=1024
#define WS_WT    16384u        // f16[8][64][128]  ([mat][n][k])
#define WS_BIAS  147456u       // f32[512]
#define WS_NODES 163840u       // f16[1088][CB][64], CB chosen at runtime

typedef unsigned int u32;
typedef unsigned long long u64;
typedef _Float16 f16;
typedef _Float16 f16x8 __attribute__((ext_vector_type(8)));
typedef float f32x4 __attribute__((ext_vector_type(4)));

#define MFMA16(a, b, c) __builtin_amdgcn_mfma_f32_16x16x32_f16((a), (b), (c), 0, 0, 0)

// ---------------- schedule kernel: level assignment + counting sort ----------------
__global__ __launch_bounds__(1024) void k_sched(const int* __restrict__ wxv,
                                                const int* __restrict__ in1v,
                                                const int* __restrict__ in2v,
                                                char* __restrict__ ws) {
  __shared__ int s1[NOPS], s2[NOPS], sw[NOPS], slv[NOPS];
  __shared__ int s_cnt[NOPS + 4];
  __shared__ int s_flag, s_nlev;
  const int j = threadIdx.x;
  s1[j] = in1v[j]; s2[j] = in2v[j]; sw[j] = wxv[j]; slv[j] = 1;
  __syncthreads();
  // monotone relaxation: lvl[j] = 1 + max(lvl(parents)); one-input ops depend only on in1
  for (int it = 0; it < NOPS + 1; ++it) {
    if (j == 0) s_flag = 0;
    __syncthreads();
    int p1 = s1[j];
    int l1 = (p1 >= NIN) ? slv[p1 - NIN] : 0;
    int l2 = 0;
    if (sw[j] >= 4) { int p2 = s2[j]; l2 = (p2 >= NIN) ? slv[p2 - NIN] : 0; }
    int nl = 1 + (l1 > l2 ? l1 : l2);
    if (nl != slv[j]) { slv[j] = nl; s_flag = 1; }
    __syncthreads();
    int f = s_flag;
    __syncthreads();
    if (!f) break;
  }
  if (j == 0) s_nlev = 0;
  __syncthreads();
  atomicMax(&s_nlev, slv[j]);
  for (int t = j; t < NOPS + 4; t += 1024) s_cnt[t] = 0;
  __syncthreads();
  atomicAdd(&s_cnt[slv[j]], 1);
  __syncthreads();
  if (j == 0) {
    int nlev = s_nlev;
    u32* wl = (u32*)(ws + WS_LEV);
    wl[0] = (u32)nlev;
    int acc = 0;
    for (int l = 1; l <= nlev; ++l) { int c = s_cnt[l]; s_cnt[l] = acc; wl[l] = (u32)acc; acc += c; }
    wl[nlev + 1] = (u32)NOPS;
  }
  __syncthreads();
  int slot = atomicAdd(&s_cnt[slv[j]], 1);   // order within a level is irrelevant (independent ops)
  u64 packed = (u64)(u32)s1[j] | ((u64)(u32)s2[j] << 11) | ((u64)(u32)sw[j] << 22) | ((u64)(u32)j << 25);
  ((u64*)(ws + WS_SCHED))[slot] = packed;
}

// ---------------- weights: unify + transpose to [mat][n][k], fp16 ----------------
__global__ __launch_bounds__(256) void k_weights(const float* __restrict__ oW,
                                                 const float* __restrict__ ob,
                                                 const float* __restrict__ tW,
                                                 const float* __restrict__ tb,
                                                 char* __restrict__ ws) {
  f16* wt = (f16*)(ws + WS_WT);
  int t = blockIdx.x * 256 + threadIdx.x;      // grid 128 -> 32768 threads, 2 elems each
  #pragma unroll
  for (int q = 0; q < 2; ++q) {
    int e = t * 2 + q;                          // e = mat*8192 + n*128 + k
    int mat = e >> 13, rem = e & 8191, n = rem >> 7, k = rem & 127;
    float v;
    if (mat < 4) v = (k < 64) ? oW[mat * 4096 + k * 64 + n] : 0.f;
    else         v = tW[(mat - 4) * 8192 + k * 64 + n];
    wt[e] = (f16)v;
  }
  if (blockIdx.x == 0) {
    float* bs = (float*)(ws + WS_BIAS);
    for (int q = threadIdx.x; q < 512; q += 256)
      bs[q] = (q < 256) ? ob[q] : tb[q - 256];
  }
}

// ---------------- leaves: embedding gather -> node slabs 0..63 (fp16) ----------------
__global__ __launch_bounds__(256) void k_leaves(const int* __restrict__ ids,
                                                const float* __restrict__ emb,
                                                char* __restrict__ ws,
                                                int cb_mask, int cbase, int sh) {
  int p = blockIdx.x * 256 + threadIdx.x;      // p over 64*CB (i,b) pairs
  int i = p >> (sh - 7);                        // CB = 1 << (sh-7)
  int b = p & cb_mask;
  int id = ids[(cbase + b) * 64 + i];
  const float* src = emb + (u32)id * 64u;
  f16* dst = (f16*)(ws + WS_NODES + ((u32)i << sh) + (u32)b * 128u);
  #pragma unroll
  for (int e = 0; e < 64; ++e) dst[e] = (f16)src[e];
}

// ---------------- main: level-ordered op evaluation, 16 rows/block ----------------
struct Slot { f16x8 a0, a1, a2, a3; int wx; u32 out; u32 bidx; };

__global__ __launch_bounds__(256, 1) void k_main(char* __restrict__ ws, int sh) {
  __shared__ u64 s_sched[NOPS];   // 8 KB
  __shared__ float s_bias[512];   // 2 KB
  const int tid = threadIdx.x;
  const u64* g_sched = (const u64*)(ws + WS_SCHED);
  for (int t = tid; t < NOPS; t += 256) s_sched[t] = g_sched[t];
  const float* g_bias = (const float*)(ws + WS_BIAS);
  for (int t = tid; t < 512; t += 256) s_bias[t] = g_bias[t];
  const u32* wl = (const u32*)(ws + WS_LEV);

  const int lane = tid & 63;
  const int w    = tid >> 6;        // wave 0..3 -> output col tile
  const int n0   = w * 16;
  const int r0   = blockIdx.x * 16; // CB/16 blocks x 16 rows (within chunk)
  const int lhi  = lane >> 4, llo = lane & 15;
  char* nodes = ws + WS_NODES;

  // A frag (16x16x32): row = llo, k = lhi*8 + j  -> byte offset lhi*16 within 64B k-half
  const u32 a_off  = (u32)((r0 + llo) * 128 + lhi * 16);
  // C/D: col = llo, row = lhi*4 + j
  const u32 st_off = (u32)((r0 + lhi * 4) * 128 + (n0 + llo) * 2);
  const u32 bias_base = (u32)(n0 + llo);

  // register-cached B fragments of all 8 weight matrices (one-input mats: only k<64 half)
  const f16* wt = (const f16*)(ws + WS_WT);
  f16x8 Bc[8][4];
  #pragma unroll
  for (int m = 0; m < 8; ++m) {
    #pragma unroll
    for (int kk = 0; kk < 4; ++kk) {
      if (m < 4 && kk >= 2) continue;
      Bc[m][kk] = *(const f16x8*)(wt + m * 8192 + (n0 + llo) * 128 + kk * 32 + lhi * 8);
    }
  }
  __syncthreads();
  const int nlev = (int)wl[0];

  auto issue = [&](Slot& S, int k, int k1) {
    if (k >= k1) return;
    u64 m = s_sched[k];
    u32 i1 = (u32)(m & 2047u);
    u32 i2 = (u32)((m >> 11) & 2047u);
    int wx = (int)((m >> 22) & 7u);
    u32 op = (u32)(m >> 25);
    S.wx = wx;
    S.out = ((64u + op) << sh) + st_off;
    S.bidx = (u32)wx * 64u + bias_base;
    const char* b1 = nodes + (i1 << sh) + a_off;
    S.a0 = *(const f16x8*)(b1);        // k in [0,32)
    S.a1 = *(const f16x8*)(b1 + 64);   // k in [32,64)  (row stride is 128B; k-half is +64B)
    if (wx >= 4) {
      const char* b2 = nodes + (i2 << sh) + a_off;
      S.a2 = *(const f16x8*)(b2);      // logical k in [64,96)
      S.a3 = *(const f16x8*)(b2 + 64); // logical k in [96,128)
    }
  };

  auto compute = [&](Slot& S, int k, int k1) {
    if (k >= k1) return;
    float bv = s_bias[S.bidx];
    f32x4 acc = {bv, bv, bv, bv};
    switch (S.wx) {
      case 0: acc = MFMA16(S.a0, Bc[0][0], acc); acc = MFMA16(S.a1, Bc[0][1], acc); break;
      case 1: acc = MFMA16(S.a0, Bc[1][0], acc); acc = MFMA16(S.a1, Bc[1][1], acc); break;
      case 2: acc = MFMA16(S.a0, Bc[2][0], acc); acc = MFMA16(S.a1, Bc[2][1], acc); break;
      case 3: acc = MFMA16(S.a0, Bc[3][0], acc); acc = MFMA16(S.a1, Bc[3][1], acc); break;
      case 4: acc = MFMA16(S.a0, Bc[4][0], acc); acc = MFMA16(S.a1, Bc[4][1], acc);
              acc = MFMA16(S.a2, Bc[4][2], acc); acc = MFMA16(S.a3, Bc[4][3], acc); break;
      case 5: acc = MFMA16(S.a0, Bc[5][0], acc); acc = MFMA16(S.a1, Bc[5][1], acc);
              acc = MFMA16(S.a2, Bc[5][2], acc); acc = MFMA16(S.a3, Bc[5][3], acc); break;
      case 6: acc = MFMA16(S.a0, Bc[6][0], acc); acc = MFMA16(S.a1, Bc[6][1], acc);
              acc = MFMA16(S.a2, Bc[6][2], acc); acc = MFMA16(S.a3, Bc[6][3], acc); break;
      default: acc = MFMA16(S.a0, Bc[7][0], acc); acc = MFMA16(S.a1, Bc[7][1], acc);
               acc = MFMA16(S.a2, Bc[7][2], acc); acc = MFMA16(S.a3, Bc[7][3], acc); break;
    }
    char* st = nodes + S.out;
    #pragma unroll
    for (int jj = 0; jj < 4; ++jj) {
      float v = acc[jj] > 0.f ? acc[jj] : 0.f;
      *(f16*)(st + jj * 128) = (f16)v;
    }
  };

  for (int l = 1; l <= nlev; ++l) {
    const int k0 = (int)wl[l], k1 = (int)wl[l + 1];
    Slot S0, S1, S2, S3;
    issue(S0, k0 + 0, k1); issue(S1, k0 + 1, k1);
    issue(S2, k0 + 2, k1); issue(S3, k0 + 3, k1);
    for (int s = k0; s < k1; s += 4) {
      compute(S0, s + 0, k1); issue(S0, s + 4, k1);
      compute(S1, s + 1, k1); issue(S1, s + 5, k1);
      compute(S2, s + 2, k1); issue(S2, s + 6, k1);
      compute(S3, s + 3, k1); issue(S3, s + 7, k1);
    }
    __syncthreads();   // level boundary: drains stores, orders RAW across waves
  }
}

// ---------------- final: out[b] = nodes[1087][b] . final_W + final_b ----------------
__global__ __launch_bounds__(256) void k_final(const float* __restrict__ fw,
                                               const float* __restrict__ fb,
                                               const char* __restrict__ ws,
                                               float* __restrict__ out,
                                               int CB, int cbase, int sh) {
  int b = blockIdx.x * 256 + threadIdx.x;
  if (b >= CB) return;
  const f16* last = (const f16*)(ws + WS_NODES + (1087u << sh)) + (u32)b * 64u;
  float acc = fb[0];
  #pragma unroll
  for (int e = 0; e < 64; ++e) acc += (float)last[e] * fw[e];
  out[cbase + b] = acc;
}

extern "C" void kernel_launch(void* const* d_in, const int* in_sizes, int n_in,
                              void* d_out, int out_size, void* d_ws, size_t ws_size,
                              hipStream_t stream) {
  const int*   ids = (const int*)d_in[0];
  const int*   wx  = (const int*)d_in[1];
  const int*   i1  = (const int*)d_in[2];
  const int*   i2  = (const int*)d_in[3];
  const float* emb = (const float*)d_in[4];
  const float* oW  = (const float*)d_in[5];
  const float* ob  = (const float*)d_in[6];
  const float* tW  = (const float*)d_in[7];
  const float* tb  = (const float*)d_in[8];
  const float* fw  = (const float*)d_in[9];
  const float* fb  = (const float*)d_in[10];
  char* ws = (char*)d_ws;
  float* out = (float*)d_out;

  // largest power-of-two chunk of batch rows whose node slab fits in ws
  u32 CB = 2048;
  while (CB > 16 && (size_t)WS_NODES + (size_t)NNODES * (size_t)CB * 128ull > ws_size) CB >>= 1;
  if ((size_t)WS_NODES + (size_t)NNODES * (size_t)CB * 128ull > ws_size) return;
  int sh = 7 + __builtin_ctz(CB);   // node slab stride = CB*128 bytes = 1<<sh
  int NC = NB / (int)CB;

  hipLaunchKernelGGL(k_sched,   dim3(1),   dim3(1024), 0, stream, wx, i1, i2, ws);
  hipLaunchKernelGGL(k_weights, dim3(128), dim3(256),  0, stream, oW, ob, tW, tb, ws);

  for (int c = 0; c < NC; ++c) {
    int cbase = c * (int)CB;
    hipLaunchKernelGGL(k_leaves, dim3((CB * 64) / 256), dim3(256), 0, stream,
                       ids, emb, ws, (int)CB - 1, cbase, sh);
    hipLaunchKernelGGL(k_main,   dim3(CB / 16),         dim3(256), 0, stream, ws, sh);
    hipLaunchKernelGGL(k_final,  dim3((CB + 255) / 256), dim3(256), 0, stream,
                       fw, fb, ws, out, (int)CB, cbase, sh);
  }
}

// Round 3
// 767.909 us; speedup vs baseline: 1.1671x; 1.1671x over previous
//
#include <hip/hip_runtime.h>

// ---- problem constants ----
#define NIN 64
#define NOPS 1024
#define NB 2048
#define NNODES 1088            // NIN + NOPS
#define SLAB_SH 18             // node slot stride = 2048 rows * 128 B = 1<<18

// ---- workspace layout (bytes) ----
#define WS_SCHED 0u            // u64[1024] packed (slot-compacted) ops
#define WS_LEV   8192u         // u32[2048]: [0]=nlev, [1..nlev+1]=level starts, [1026]=slot1087, [1027]=err
#define WS_WT    16384u        // f16[8][64][128]  ([mat][n][k])
#define WS_BIAS  147456u       // f32[512]
#define WS_NODES 163840u       // f16[cap][2048][64] slot slabs

typedef unsigned int u32;
typedef unsigned long long u64;
typedef _Float16 f16;
typedef _Float16 f16x8 __attribute__((ext_vector_type(8)));
typedef _Float16 f16x4 __attribute__((ext_vector_type(4)));
typedef float f32x4 __attribute__((ext_vector_type(4)));

#define MFMA16(a, b, c) __builtin_amdgcn_mfma_f32_16x16x32_f16((a), (b), (c), 0, 0, 0)

// ---------------- schedule: levels + counting sort + liveness slot allocation ----------------
__global__ __launch_bounds__(1024) void k_sched(const int* __restrict__ wxv,
                                                const int* __restrict__ in1v,
                                                const int* __restrict__ in2v,
                                                char* __restrict__ ws, int cap) {
  __shared__ int s1[NOPS], s2[NOPS], sw[NOPS], slv[NOPS];
  __shared__ int s_cnt[NOPS + 4];
  __shared__ u64 s_pack[NOPS];
  __shared__ int dl[NNODES], slot_of[NNODES], stk[NNODES];
  __shared__ int s_flag, s_nlev, s_top, s_next;
  const int j = threadIdx.x;
  s1[j] = in1v[j]; s2[j] = in2v[j]; sw[j] = wxv[j]; slv[j] = 1;
  __syncthreads();
  // monotone relaxation: lvl[j] = 1 + max(lvl(parents))
  for (int it = 0; it < NOPS + 1; ++it) {
    if (j == 0) s_flag = 0;
    __syncthreads();
    int p1 = s1[j];
    int l1 = (p1 >= NIN) ? slv[p1 - NIN] : 0;
    int l2 = 0;
    if (sw[j] >= 4) { int p2 = s2[j]; l2 = (p2 >= NIN) ? slv[p2 - NIN] : 0; }
    int nl = 1 + (l1 > l2 ? l1 : l2);
    if (nl != slv[j]) { slv[j] = nl; s_flag = 1; }
    __syncthreads();
    int f = s_flag;
    __syncthreads();
    if (!f) break;
  }
  if (j == 0) s_nlev = 0;
  __syncthreads();
  atomicMax(&s_nlev, slv[j]);
  for (int t = j; t < NOPS + 4; t += 1024) s_cnt[t] = 0;
  __syncthreads();
  atomicAdd(&s_cnt[slv[j]], 1);
  __syncthreads();
  u32* wl = (u32*)(ws + WS_LEV);
  if (j == 0) {
    int nlev = s_nlev;
    wl[0] = (u32)nlev;
    int acc = 0;
    for (int l = 1; l <= nlev; ++l) { int c = s_cnt[l]; s_cnt[l] = acc; wl[l] = (u32)acc; acc += c; }
    wl[nlev + 1] = (u32)NOPS;
  }
  __syncthreads();
  { int slot = atomicAdd(&s_cnt[slv[j]], 1);
    u64 p = (u64)(u32)s1[j] | ((u64)(u32)s2[j] << 11) | ((u64)(u32)sw[j] << 22) | ((u64)(u32)j << 25);
    s_pack[slot] = p; }
  // death levels
  for (int t = j; t < NNODES; t += 1024) dl[t] = (t < NIN) ? 0 : slv[t - NIN];
  __syncthreads();
  atomicMax(&dl[s1[j]], slv[j]);
  if (sw[j] >= 4) atomicMax(&dl[s2[j]], slv[j]);
  __syncthreads();
  if (j == 0) { dl[NNODES - 1] = s_nlev + 1; s_top = 0; s_next = NIN; }
  if (j < NIN) slot_of[j] = j;
  __syncthreads();
  const int nlev = s_nlev;
  // greedy interval-coloring by level: free (dl == L-1) then allocate (slv == L)
  for (int L = 1; L <= nlev; ++L) {
    for (int t = j; t < NNODES; t += 1024)
      if (dl[t] == L - 1) { int p = atomicAdd(&s_top, 1); stk[p] = slot_of[t]; }
    __syncthreads();
    if (slv[j] == L) {
      int p = atomicSub(&s_top, 1);
      int s;
      if (p >= 1) s = stk[p - 1]; else s = atomicAdd(&s_next, 1);
      slot_of[NIN + j] = s;
    }
    __syncthreads();
    if (j == 0 && s_top < 0) s_top = 0;
    __syncthreads();
  }
  // rewrite schedule entries with slot indices
  u64 m = s_pack[j];
  int i1n = (int)(m & 2047u), i2n = (int)((m >> 11) & 2047u);
  u32 wxn = (u32)((m >> 22) & 7u), opn = (u32)((m >> 25) & 2047u);
  u64 nm = (u64)(u32)slot_of[i1n] | ((u64)(u32)slot_of[i2n] << 11)
         | ((u64)wxn << 22) | ((u64)(u32)slot_of[NIN + opn] << 25);
  ((u64*)(ws + WS_SCHED))[j] = nm;
  if (j == 0) {
    wl[1026] = (u32)slot_of[NNODES - 1];          // slot holding final node 1087
    wl[1027] = (s_next > cap) ? 1u : 0u;          // capacity error flag (visible failure)
  }
}

// ---------------- weights: unify + transpose to [mat][n][k], fp16 ----------------
__global__ __launch_bounds__(256) void k_weights(const float* __restrict__ oW,
                                                 const float* __restrict__ ob,
                                                 const float* __restrict__ tW,
                                                 const float* __restrict__ tb,
                                                 char* __restrict__ ws) {
  f16* wt = (f16*)(ws + WS_WT);
  int t = blockIdx.x * 256 + threadIdx.x;
  #pragma unroll
  for (int q = 0; q < 2; ++q) {
    int e = t * 2 + q;                          // e = mat*8192 + n*128 + k
    int mat = e >> 13, rem = e & 8191, n = rem >> 7, k = rem & 127;
    float v;
    if (mat < 4) v = (k < 64) ? oW[mat * 4096 + k * 64 + n] : 0.f;
    else         v = tW[(mat - 4) * 8192 + k * 64 + n];
    wt[e] = (f16)v;
  }
  if (blockIdx.x == 0) {
    float* bs = (float*)(ws + WS_BIAS);
    for (int q = threadIdx.x; q < 512; q += 256)
      bs[q] = (q < 256) ? ob[q] : tb[q - 256];
  }
}

// ---------------- leaves: embedding gather -> slots 0..63 (fp16, vectorized) ----------------
__global__ __launch_bounds__(256) void k_leaves(const int* __restrict__ ids,
                                                const float* __restrict__ emb,
                                                char* __restrict__ ws) {
  int p = blockIdx.x * 256 + threadIdx.x;      // 131072 (i,b) pairs
  int i = p >> 11, b = p & 2047;
  int id = ids[b * 64 + i];
  const f32x4* src = (const f32x4*)(emb + (u32)id * 64u);
  f16x8* dst = (f16x8*)(ws + WS_NODES + ((u32)i << SLAB_SH) + (u32)b * 128u);
  #pragma unroll
  for (int q = 0; q < 8; ++q) {
    f32x4 lo = src[2 * q], hi = src[2 * q + 1];
    f16x8 v = { (f16)lo.x, (f16)lo.y, (f16)lo.z, (f16)lo.w,
                (f16)hi.x, (f16)hi.y, (f16)hi.z, (f16)hi.w };
    dst[q] = v;
  }
}

// ---------------- main: 128 blocks x 1024 thr (4 op-groups x 4 col-tiles) ----------------
struct Slot { f16x8 a0, a1, a2, a3; u32 wxo; u32 out; };

__global__ __launch_bounds__(1024) void k_main(char* __restrict__ ws) {
  __shared__ u64 s_sched[NOPS];   // 8 KB
  __shared__ float s_bias[512];   // 2 KB
  const int tid = threadIdx.x;
  const u32* wl = (const u32*)(ws + WS_LEV);
  s_sched[tid] = ((const u64*)(ws + WS_SCHED))[tid];
  if (tid < 512) s_bias[tid] = ((const float*)(ws + WS_BIAS))[tid];
  const int nlev = (int)wl[0];
  const u32 err = wl[1027];
  __syncthreads();
  if (err) return;

  const int lane = tid & 63;
  const int w  = tid >> 6;          // 16 waves
  const int g  = w >> 2;            // op-group 0..3 (ops strided by 4 within level)
  const int ct = w & 3;             // col-tile 0..3
  const int n0 = ct * 16;
  const int r0 = blockIdx.x * 16;   // 128 blocks x 16 batch rows
  const int lhi = lane >> 4, llo = lane & 15;
  char* nodes = ws + WS_NODES;
  const f16* wt = (const f16*)(ws + WS_WT);

  // x as B-operand: col=llo (batch row), k = chunk*32 + lhi*8 + j
  const u32 a_off  = (u32)((r0 + llo) * 128 + lhi * 16);
  // D: col=llo (batch row), row = n = n0 + lhi*4 + j  -> 8B contiguous store
  const u32 st_off = (u32)((r0 + llo) * 128 + (n0 + lhi * 4) * 2);
  // W as A-operand: row=llo (n), k = chunk*32 + lhi*8 + j
  const u32 wk_off = (u32)((n0 + llo) * 128 + lhi * 8);
  const u32 b_off  = (u32)(n0 + lhi * 4);

  auto issue = [&](Slot& S, int k, int k1) {
    if (k >= k1) return;
    u64 m = s_sched[k];
    u32 i1 = (u32)m & 2047u;
    u32 i2 = (u32)(m >> 11) & 2047u;
    u32 wx = (u32)(m >> 22) & 7u;
    u32 os = (u32)(m >> 25) & 2047u;
    S.wxo = wx * 8192u;
    S.out = (os << SLAB_SH) + st_off;
    const char* b1 = nodes + (i1 << SLAB_SH) + a_off;
    S.a0 = *(const f16x8*)(b1);
    S.a1 = *(const f16x8*)(b1 + 64);
    if (wx >= 4) {
      const char* b2 = nodes + (i2 << SLAB_SH) + a_off;
      S.a2 = *(const f16x8*)(b2);
      S.a3 = *(const f16x8*)(b2 + 64);
    }
  };

  auto computeA = [&](Slot& S, int k, int k1, f16x4& res) {
    if (k >= k1) return;
    const f16* wp = wt + S.wxo + wk_off;
    f32x4 acc = *(const f32x4*)(&s_bias[(S.wxo >> 7) + b_off]);
    f16x8 w0 = *(const f16x8*)(wp);
    f16x8 w1 = *(const f16x8*)(wp + 32);
    acc = MFMA16(w0, S.a0, acc);
    acc = MFMA16(w1, S.a1, acc);
    if (S.wxo >= 32768u) {
      f16x8 w2 = *(const f16x8*)(wp + 64);
      f16x8 w3 = *(const f16x8*)(wp + 96);
      acc = MFMA16(w2, S.a2, acc);
      acc = MFMA16(w3, S.a3, acc);
    }
    f16x4 r = { (f16)(acc.x > 0.f ? acc.x : 0.f), (f16)(acc.y > 0.f ? acc.y : 0.f),
                (f16)(acc.z > 0.f ? acc.z : 0.f), (f16)(acc.w > 0.f ? acc.w : 0.f) };
    res = r;
  };

  for (int L = 1; L <= nlev; ++L) {
    const int k0 = (int)wl[L], k1 = (int)wl[L + 1];
    const int kb = k0 + g;
    Slot S0, S1, S2, S3;
    issue(S0, kb, k1); issue(S1, kb + 4, k1);
    issue(S2, kb + 8, k1); issue(S3, kb + 12, k1);
    for (int kk = kb; kk < k1; kk += 16) {
      f16x4 q0, q1, q2, q3;
      computeA(S0, kk,      k1, q0);
      computeA(S1, kk + 4,  k1, q1);
      computeA(S2, kk + 8,  k1, q2);
      computeA(S3, kk + 12, k1, q3);
      u32 o0 = S0.out, o1 = S1.out, o2 = S2.out, o3 = S3.out;
      issue(S0, kk + 16, k1); issue(S1, kk + 20, k1);
      issue(S2, kk + 24, k1); issue(S3, kk + 28, k1);
      if (kk      < k1) *(f16x4*)(nodes + o0) = q0;
      if (kk + 4  < k1) *(f16x4*)(nodes + o1) = q1;
      if (kk + 8  < k1) *(f16x4*)(nodes + o2) = q2;
      if (kk + 12 < k1) *(f16x4*)(nodes + o3) = q3;
    }
    __syncthreads();   // level boundary
  }
}

// ---------------- final: out[b] = nodes[slot1087][b] . final_W + final_b ----------------
__global__ __launch_bounds__(256) void k_final(const float* __restrict__ fw,
                                               const float* __restrict__ fb,
                                               const char* __restrict__ ws,
                                               float* __restrict__ out) {
  __shared__ float s_fw[64];
  int t = threadIdx.x;
  if (t < 64) s_fw[t] = fw[t];
  __syncthreads();
  int b = blockIdx.x * 256 + t;
  const u32* wl = (const u32*)(ws + WS_LEV);
  if (wl[1027]) { out[b] = 0.f; return; }
  u32 slot = wl[1026];
  const f16x8* last = (const f16x8*)(ws + WS_NODES + ((u64)slot << SLAB_SH) + (u32)b * 128u);
  float acc = fb[0];
  #pragma unroll
  for (int q = 0; q < 8; ++q) {
    f16x8 v = last[q];
    #pragma unroll
    for (int e = 0; e < 8; ++e) acc += (float)v[e] * s_fw[q * 8 + e];
  }
  out[b] = acc;
}

extern "C" void kernel_launch(void* const* d_in, const int* in_sizes, int n_in,
                              void* d_out, int out_size, void* d_ws, size_t ws_size,
                              hipStream_t stream) {
  const int*   ids = (const int*)d_in[0];
  const int*   wx  = (const int*)d_in[1];
  const int*   i1  = (const int*)d_in[2];
  const int*   i2  = (const int*)d_in[3];
  const float* emb = (const float*)d_in[4];
  const float* oW  = (const float*)d_in[5];
  const float* ob  = (const float*)d_in[6];
  const float* tW  = (const float*)d_in[7];
  const float* tb  = (const float*)d_in[8];
  const float* fw  = (const float*)d_in[9];
  const float* fb  = (const float*)d_in[10];
  char* ws = (char*)d_ws;
  float* out = (float*)d_out;

  // slot capacity from workspace size (node slab stride fixed at 2048*128 B)
  int cap = (int)((ws_size > (size_t)WS_NODES) ? ((ws_size - WS_NODES) >> SLAB_SH) : 0);
  if (cap < 80) return;   // hopeless workspace: visible failure (zeros)

  hipLaunchKernelGGL(k_sched,   dim3(1),   dim3(1024), 0, stream, wx, i1, i2, ws, cap);
  hipLaunchKernelGGL(k_weights, dim3(128), dim3(256),  0, stream, oW, ob, tW, tb, ws);
  hipLaunchKernelGGL(k_leaves,  dim3(512), dim3(256),  0, stream, ids, emb, ws);
  hipLaunchKernelGGL(k_main,    dim3(128), dim3(1024), 0, stream, ws);
  hipLaunchKernelGGL(k_final,   dim3(8),   dim3(256),  0, stream, fw, fb, ws, out);
}

// Round 4
// 540.702 us; speedup vs baseline: 1.6575x; 1.4202x over previous
//
#include <hip/hip_runtime.h>

// ---- problem constants ----
#define NIN 64
#define NOPS 1024
#define NB 2048
#define NNODES 1088            // NIN + NOPS
#define SLAB_SH 18             // node slot stride = 2048 rows * 128 B = 1<<18

// ---- workspace layout (bytes) ----
#define WS_SCHED 0u            // u64[1024] packed (slot-compacted) ops
#define WS_LEV   8192u         // u32[2048]: [0]=nlev, [1..nlev+1]=level starts, [1026]=slot1087, [1027]=err
#define WS_WT    16384u        // swizzled W: mats0-3 (k<64 only) 4*8KB, mats4-7 4*16KB = 96KB
#define WS_BIAS  114688u       // f32[512]
#define WS_NODES 163840u       // f16[cap][2048][64] slot slabs

// ---- k_main LDS layout (dynamic, bytes) ----
#define L_WT    0u             // 98304 B (96KB) swizzled W
#define L_SCHED 98304u         // u64[1024] = 8KB
#define L_BIAS  106496u        // f32[512]  = 2KB
#define L_LEV   108544u        // u32[256]  = 1KB
#define L_TOTAL 109568u

typedef unsigned int u32;
typedef unsigned long long u64;
typedef _Float16 f16;
typedef _Float16 f16x8 __attribute__((ext_vector_type(8)));
typedef _Float16 f16x4 __attribute__((ext_vector_type(4)));
typedef float f32x4 __attribute__((ext_vector_type(4)));

#define MFMA16(a, b, c) __builtin_amdgcn_mfma_f32_16x16x32_f16((a), (b), (c), 0, 0, 0)

// ---------------- schedule: levels + counting sort + liveness slot allocation ----------------
__global__ __launch_bounds__(1024) void k_sched(const int* __restrict__ wxv,
                                                const int* __restrict__ in1v,
                                                const int* __restrict__ in2v,
                                                char* __restrict__ ws, int cap) {
  __shared__ int s1[NOPS], s2[NOPS], sw[NOPS], slv[NOPS];
  __shared__ int s_cnt[NOPS + 4];
  __shared__ u64 s_pack[NOPS];
  __shared__ int dl[NNODES], slot_of[NNODES], stk[NNODES];
  __shared__ int s_flag, s_nlev, s_top, s_next;
  const int j = threadIdx.x;
  s1[j] = in1v[j]; s2[j] = in2v[j]; sw[j] = wxv[j]; slv[j] = 1;
  __syncthreads();
  for (int it = 0; it < NOPS + 1; ++it) {
    if (j == 0) s_flag = 0;
    __syncthreads();
    int p1 = s1[j];
    int l1 = (p1 >= NIN) ? slv[p1 - NIN] : 0;
    int l2 = 0;
    if (sw[j] >= 4) { int p2 = s2[j]; l2 = (p2 >= NIN) ? slv[p2 - NIN] : 0; }
    int nl = 1 + (l1 > l2 ? l1 : l2);
    if (nl != slv[j]) { slv[j] = nl; s_flag = 1; }
    __syncthreads();
    int f = s_flag;
    __syncthreads();
    if (!f) break;
  }
  if (j == 0) s_nlev = 0;
  __syncthreads();
  atomicMax(&s_nlev, slv[j]);
  for (int t = j; t < NOPS + 4; t += 1024) s_cnt[t] = 0;
  __syncthreads();
  atomicAdd(&s_cnt[slv[j]], 1);
  __syncthreads();
  u32* wl = (u32*)(ws + WS_LEV);
  if (j == 0) {
    int nlev = s_nlev;
    wl[0] = (u32)nlev;
    int acc = 0;
    for (int l = 1; l <= nlev; ++l) { int c = s_cnt[l]; s_cnt[l] = acc; wl[l] = (u32)acc; acc += c; }
    wl[nlev + 1] = (u32)NOPS;
  }
  __syncthreads();
  { int slot = atomicAdd(&s_cnt[slv[j]], 1);
    u64 p = (u64)(u32)s1[j] | ((u64)(u32)s2[j] << 11) | ((u64)(u32)sw[j] << 22) | ((u64)(u32)j << 25);
    s_pack[slot] = p; }
  // death levels
  for (int t = j; t < NNODES; t += 1024) dl[t] = (t < NIN) ? 0 : slv[t - NIN];
  __syncthreads();
  atomicMax(&dl[s1[j]], slv[j]);
  if (sw[j] >= 4) atomicMax(&dl[s2[j]], slv[j]);
  __syncthreads();
  if (j == 0) { dl[NNODES - 1] = s_nlev + 1; s_top = 0; s_next = NIN; }
  if (j < NIN) slot_of[j] = j;
  __syncthreads();
  const int nlev = s_nlev;
  for (int L = 1; L <= nlev; ++L) {
    for (int t = j; t < NNODES; t += 1024)
      if (dl[t] == L - 1) { int p = atomicAdd(&s_top, 1); stk[p] = slot_of[t]; }
    __syncthreads();
    if (slv[j] == L) {
      int p = atomicSub(&s_top, 1);
      int s;
      if (p >= 1) s = stk[p - 1]; else s = atomicAdd(&s_next, 1);
      slot_of[NIN + j] = s;
    }
    __syncthreads();
    if (j == 0 && s_top < 0) s_top = 0;
    __syncthreads();
  }
  u64 m = s_pack[j];
  int i1n = (int)(m & 2047u), i2n = (int)((m >> 11) & 2047u);
  u32 wxn = (u32)((m >> 22) & 7u), opn = (u32)((m >> 25) & 2047u);
  u64 nm = (u64)(u32)slot_of[i1n] | ((u64)(u32)slot_of[i2n] << 11)
         | ((u64)wxn << 22) | ((u64)(u32)slot_of[NIN + opn] << 25);
  ((u64*)(ws + WS_SCHED))[j] = nm;
  if (j == 0) {
    wl[1026] = (u32)slot_of[NNODES - 1];
    wl[1027] = (s_next > cap || s_nlev > 254) ? 1u : 0u;
  }
}

// ---------------- weights: unify + transpose + XOR-swizzle into global staging ----------------
// layout: mat<4: base=mat*8192,  row n: 128B (k<64 only);  mat>=4: base=32768+(mat-4)*16384, row n: 256B
// within row: byte = (k*2) ^ ((n&7)<<4)
__global__ __launch_bounds__(256) void k_weights(const float* __restrict__ oW,
                                                 const float* __restrict__ ob,
                                                 const float* __restrict__ tW,
                                                 const float* __restrict__ tb,
                                                 char* __restrict__ ws) {
  f16* wt = (f16*)(ws + WS_WT);
  int t = blockIdx.x * 256 + threadIdx.x;   // 64 blocks -> 16384 threads, 3 elems each
  #pragma unroll
  for (int q = 0; q < 3; ++q) {
    int e = t * 3 + q;
    if (e < 16384) {                         // one-input mats, k<64
      int mat = e >> 12, n = (e >> 6) & 63, k = e & 63;
      u32 off = (u32)mat * 8192u + (u32)n * 128u + (u32)((k * 2) ^ ((n & 7) << 4));
      *(f16*)((char*)wt + off) = (f16)oW[mat * 4096 + k * 64 + n];
    } else if (e < 49152) {                  // two-input mats, k<128
      int f = e - 16384;
      int mat4 = f >> 13, n = (f >> 7) & 63, k = f & 127;
      u32 off = 32768u + (u32)mat4 * 16384u + (u32)n * 256u + (u32)((k * 2) ^ ((n & 7) << 4));
      *(f16*)((char*)wt + off) = (f16)tW[mat4 * 8192 + k * 64 + n];
    }
  }
  if (blockIdx.x == 0) {
    float* bs = (float*)(ws + WS_BIAS);
    for (int q = threadIdx.x; q < 512; q += 256)
      bs[q] = (q < 256) ? ob[q] : tb[q - 256];
  }
}

// ---------------- leaves: embedding gather -> slots 0..63 (fp16, vectorized) ----------------
__global__ __launch_bounds__(256) void k_leaves(const int* __restrict__ ids,
                                                const float* __restrict__ emb,
                                                char* __restrict__ ws) {
  int p = blockIdx.x * 256 + threadIdx.x;      // 131072 (i,b) pairs
  int i = p >> 11, b = p & 2047;
  int id = ids[b * 64 + i];
  const f32x4* src = (const f32x4*)(emb + (u32)id * 64u);
  f16x8* dst = (f16x8*)(ws + WS_NODES + ((u32)i << SLAB_SH) + (u32)b * 128u);
  #pragma unroll
  for (int q = 0; q < 8; ++q) {
    f32x4 lo = src[2 * q], hi = src[2 * q + 1];
    f16x8 v = { (f16)lo.x, (f16)lo.y, (f16)lo.z, (f16)lo.w,
                (f16)hi.x, (f16)hi.y, (f16)hi.z, (f16)hi.w };
    dst[q] = v;
  }
}

// ---------------- main: 256 blocks x 8 rows, W/sched/bias in LDS, depth-2 pipeline ----------------
struct Slot { f16x8 a0, a1, a2, a3, w0, w1, w2, w3; f32x4 bias; u64 oaddr; bool two; };

__global__ __launch_bounds__(1024, 4) void k_main(char* __restrict__ ws) {
  extern __shared__ char lds[];
  const int tid = threadIdx.x;
  const u32* wl = (const u32*)(ws + WS_LEV);
  if (wl[1027]) return;            // uniform early-out before any barrier

  // stage W (linear 16B copy of pre-swizzled global), sched, bias, levels
  {
    const f16x8* gw = (const f16x8*)(ws + WS_WT);
    f16x8* lw = (f16x8*)(lds + L_WT);
    for (int u = tid; u < 6144; u += 1024) lw[u] = gw[u];
    ((u64*)(lds + L_SCHED))[tid] = ((const u64*)(ws + WS_SCHED))[tid];
    if (tid < 512) ((float*)(lds + L_BIAS))[tid] = ((const float*)(ws + WS_BIAS))[tid];
    if (tid < 256) ((u32*)(lds + L_LEV))[tid] = wl[tid];
  }
  __syncthreads();

  const u64*   s_sched = (const u64*)(lds + L_SCHED);
  const float* s_bias  = (const float*)(lds + L_BIAS);
  const u32*   s_lev   = (const u32*)(lds + L_LEV);
  const int nlev = (int)s_lev[0];

  const int lane = tid & 63;
  const int w  = tid >> 6;          // 16 waves
  const int g  = w >> 2;            // op-group 0..3
  const int ct = w & 3;             // col-tile 0..3
  const int n0 = ct * 16;
  const int r0 = blockIdx.x * 8;    // 256 blocks x 8 batch rows
  const int lhi = lane >> 4, llo = lane & 15;
  char* nodes = ws + WS_NODES;

  // x as B-operand: col=llo -> batch row (dup llo&7), k = lhi*8+j per 32-k chunk
  const u32 a_off  = (u32)((r0 + (llo & 7)) * 128 + lhi * 16);
  // D: col=llo (batch row), rows n = n0+lhi*4+j -> 8B store, llo<8 only
  const u32 st_off = (u32)((r0 + llo) * 128 + (n0 + lhi * 4) * 2);
  const int n_me   = n0 + llo;                 // W row this lane supplies (A-operand row)
  const u32 roA    = (u32)(n_me * 128);        // one-input row stride
  const u32 roB    = (u32)(n_me * 256);        // two-input row stride
  const u32 swz    = (u32)((n_me & 7) << 4);
  const u32 bq     = (u32)(n0 + lhi * 4);

  auto loadS = [&](Slot& S, int k, int k1) {
    int kc = k < k1 ? k : k1 - 1;
    u64 m = s_sched[kc];
    u32 i1 = (u32)m & 2047u;
    u32 i2 = ((u32)(m >> 11)) & 2047u;
    u32 wx = ((u32)(m >> 22)) & 7u;
    u32 os = ((u32)(m >> 25)) & 2047u;
    S.two = wx >= 4;
    const char* b1 = nodes + ((u64)i1 << SLAB_SH) + a_off;
    S.a0 = *(const f16x8*)(b1);
    S.a1 = *(const f16x8*)(b1 + 64);
    const char* b2 = nodes + ((u64)i2 << SLAB_SH) + a_off;
    S.a2 = *(const f16x8*)(b2);
    S.a3 = *(const f16x8*)(b2 + 64);
    u32 wb = S.two ? (32768u + (wx - 4) * 16384u + roB) : (wx * 8192u + roA);
    S.w0 = *(const f16x8*)(lds + wb + ((lhi * 16 +   0) ^ swz));
    S.w1 = *(const f16x8*)(lds + wb + ((lhi * 16 +  64) ^ swz));
    if (S.two) {
      S.w2 = *(const f16x8*)(lds + wb + ((lhi * 16 + 128) ^ swz));
      S.w3 = *(const f16x8*)(lds + wb + ((lhi * 16 + 192) ^ swz));
    }
    S.bias = *(const f32x4*)(s_bias + wx * 64u + bq);
    S.oaddr = ((u64)os << SLAB_SH) + st_off;
  };

  auto computeS = [&](Slot& S) {
    f32x4 acc = S.bias;
    acc = MFMA16(S.w0, S.a0, acc);
    acc = MFMA16(S.w1, S.a1, acc);
    if (S.two) {
      acc = MFMA16(S.w2, S.a2, acc);
      acc = MFMA16(S.w3, S.a3, acc);
    }
    f16x4 r = { (f16)(acc.x > 0.f ? acc.x : 0.f), (f16)(acc.y > 0.f ? acc.y : 0.f),
                (f16)(acc.z > 0.f ? acc.z : 0.f), (f16)(acc.w > 0.f ? acc.w : 0.f) };
    if (llo < 8) *(f16x4*)(nodes + S.oaddr) = r;
  };

  for (int L = 1; L <= nlev; ++L) {
    const int k0 = (int)s_lev[L], k1 = (int)s_lev[L + 1];
    const int kb = k0 + g;
    Slot A, B;
    loadS(A, kb, k1);
    for (int k = kb; k < k1; k += 8) {
      loadS(B, k + 4, k1);
      computeS(A);
      loadS(A, k + 8, k1);
      if (k + 4 < k1) computeS(B);
    }
    __syncthreads();   // level boundary
  }
}

// ---------------- final: out[b] = nodes[slot1087][b] . final_W + final_b ----------------
__global__ __launch_bounds__(256) void k_final(const float* __restrict__ fw,
                                               const float* __restrict__ fb,
                                               const char* __restrict__ ws,
                                               float* __restrict__ out) {
  __shared__ float s_fw[64];
  int t = threadIdx.x;
  if (t < 64) s_fw[t] = fw[t];
  __syncthreads();
  int b = blockIdx.x * 256 + t;
  const u32* wl = (const u32*)(ws + WS_LEV);
  if (wl[1027]) { out[b] = 0.f; return; }
  u32 slot = wl[1026];
  const f16x8* last = (const f16x8*)(ws + WS_NODES + ((u64)slot << SLAB_SH) + (u32)b * 128u);
  float acc = fb[0];
  #pragma unroll
  for (int q = 0; q < 8; ++q) {
    f16x8 v = last[q];
    #pragma unroll
    for (int e = 0; e < 8; ++e) acc += (float)v[e] * s_fw[q * 8 + e];
  }
  out[b] = acc;
}

extern "C" void kernel_launch(void* const* d_in, const int* in_sizes, int n_in,
                              void* d_out, int out_size, void* d_ws, size_t ws_size,
                              hipStream_t stream) {
  const int*   ids = (const int*)d_in[0];
  const int*   wx  = (const int*)d_in[1];
  const int*   i1  = (const int*)d_in[2];
  const int*   i2  = (const int*)d_in[3];
  const float* emb = (const float*)d_in[4];
  const float* oW  = (const float*)d_in[5];
  const float* ob  = (const float*)d_in[6];
  const float* tW  = (const float*)d_in[7];
  const float* tb  = (const float*)d_in[8];
  const float* fw  = (const float*)d_in[9];
  const float* fb  = (const float*)d_in[10];
  char* ws = (char*)d_ws;
  float* out = (float*)d_out;

  int cap = (int)((ws_size > (size_t)WS_NODES) ? ((ws_size - WS_NODES) >> SLAB_SH) : 0);
  if (cap < 80) return;
  if (cap > 2047) cap = 2047;

  hipLaunchKernelGGL(k_sched,   dim3(1),   dim3(1024), 0, stream, wx, i1, i2, ws, cap);
  hipLaunchKernelGGL(k_weights, dim3(64),  dim3(256),  0, stream, oW, ob, tW, tb, ws);
  hipLaunchKernelGGL(k_leaves,  dim3(512), dim3(256),  0, stream, ids, emb, ws);
  hipLaunchKernelGGL(k_main,    dim3(256), dim3(1024), L_TOTAL, stream, ws);
  hipLaunchKernelGGL(k_final,   dim3(8),   dim3(256),  0, stream, fw, fb, ws, out);
}

// Round 5
// 538.573 us; speedup vs baseline: 1.6640x; 1.0040x over previous
//
#include <hip/hip_runtime.h>

// ---- problem constants ----
#define NIN 64
#define NOPS 1024
#define NB 2048
#define NNODES 1088            // NIN + NOPS
#define SLAB_SH 18             // node slot stride = 2048 rows * 128 B = 1<<18

// ---- workspace layout (bytes) ----
#define WS_SCHED 0u            // u64[1024] packed (slot-compacted) ops
#define WS_LEV   8192u         // u32[2048]: [0]=nlev, [1..nlev+1]=level starts, [1026]=slot1087, [1027]=err
#define WS_WT    16384u        // swizzled W_pad: f16[8][64][128], 256B rows -> 128KB
#define WS_BIAS  147456u       // f32[512]
#define WS_NODES 163840u       // f16[cap][2048][64] slot slabs

// ---- k_main LDS layout (dynamic, bytes) ----
#define L_WT    0u             // 131072 B (128KB) swizzled W_pad
#define L_SCHED 131072u        // u64[1024] = 8KB
#define L_BIAS  139264u        // f32[512]  = 2KB
#define L_LEV   141312u        // u32[256]  = 1KB
#define L_TOTAL 142336u

typedef unsigned int u32;
typedef unsigned long long u64;
typedef _Float16 f16;
typedef _Float16 f16x8 __attribute__((ext_vector_type(8)));
typedef _Float16 f16x4 __attribute__((ext_vector_type(4)));
typedef float f32x4 __attribute__((ext_vector_type(4)));

#define MFMA16(a, b, c) __builtin_amdgcn_mfma_f32_16x16x32_f16((a), (b), (c), 0, 0, 0)

// ---------------- schedule: levels + counting sort + liveness slot allocation ----------------
__global__ __launch_bounds__(1024) void k_sched(const int* __restrict__ wxv,
                                                const int* __restrict__ in1v,
                                                const int* __restrict__ in2v,
                                                char* __restrict__ ws, int cap) {
  __shared__ int s1[NOPS], s2[NOPS], sw[NOPS], slv[NOPS];
  __shared__ int s_cnt[NOPS + 4];
  __shared__ u64 s_pack[NOPS];
  __shared__ int dl[NNODES], slot_of[NNODES], stk[NNODES];
  __shared__ int s_flag, s_nlev, s_top, s_next;
  const int j = threadIdx.x;
  s1[j] = in1v[j]; s2[j] = in2v[j]; sw[j] = wxv[j]; slv[j] = 1;
  __syncthreads();
  for (int it = 0; it < NOPS + 1; ++it) {
    if (j == 0) s_flag = 0;
    __syncthreads();
    int p1 = s1[j];
    int l1 = (p1 >= NIN) ? slv[p1 - NIN] : 0;
    int l2 = 0;
    if (sw[j] >= 4) { int p2 = s2[j]; l2 = (p2 >= NIN) ? slv[p2 - NIN] : 0; }
    int nl = 1 + (l1 > l2 ? l1 : l2);
    if (nl != slv[j]) { slv[j] = nl; s_flag = 1; }
    __syncthreads();
    int f = s_flag;
    __syncthreads();
    if (!f) break;
  }
  if (j == 0) s_nlev = 0;
  __syncthreads();
  atomicMax(&s_nlev, slv[j]);
  for (int t = j; t < NOPS + 4; t += 1024) s_cnt[t] = 0;
  __syncthreads();
  atomicAdd(&s_cnt[slv[j]], 1);
  __syncthreads();
  u32* wl = (u32*)(ws + WS_LEV);
  if (j == 0) {
    int nlev = s_nlev;
    wl[0] = (u32)nlev;
    int acc = 0;
    for (int l = 1; l <= nlev; ++l) { int c = s_cnt[l]; s_cnt[l] = acc; wl[l] = (u32)acc; acc += c; }
    wl[nlev + 1] = (u32)NOPS;
  }
  __syncthreads();
  { int slot = atomicAdd(&s_cnt[slv[j]], 1);
    u64 p = (u64)(u32)s1[j] | ((u64)(u32)s2[j] << 11) | ((u64)(u32)sw[j] << 22) | ((u64)(u32)j << 25);
    s_pack[slot] = p; }
  // death levels
  for (int t = j; t < NNODES; t += 1024) dl[t] = (t < NIN) ? 0 : slv[t - NIN];
  __syncthreads();
  atomicMax(&dl[s1[j]], slv[j]);
  if (sw[j] >= 4) atomicMax(&dl[s2[j]], slv[j]);
  __syncthreads();
  if (j == 0) { dl[NNODES - 1] = s_nlev + 1; s_top = 0; s_next = NIN; }
  if (j < NIN) slot_of[j] = j;
  __syncthreads();
  const int nlev = s_nlev;
  for (int L = 1; L <= nlev; ++L) {
    for (int t = j; t < NNODES; t += 1024)
      if (dl[t] == L - 1) { int p = atomicAdd(&s_top, 1); stk[p] = slot_of[t]; }
    __syncthreads();
    if (slv[j] == L) {
      int p = atomicSub(&s_top, 1);
      int s;
      if (p >= 1) s = stk[p - 1]; else s = atomicAdd(&s_next, 1);
      slot_of[NIN + j] = s;
    }
    __syncthreads();
    if (j == 0 && s_top < 0) s_top = 0;
    __syncthreads();
  }
  u64 m = s_pack[j];
  int i1n = (int)(m & 2047u), i2n = (int)((m >> 11) & 2047u);
  u32 wxn = (u32)((m >> 22) & 7u), opn = (u32)((m >> 25) & 2047u);
  u32 s1slot = (u32)slot_of[i1n];
  u32 s2slot = (wxn >= 4) ? (u32)slot_of[i2n] : s1slot;   // one-input: i2:=i1 (zero W-half; guaranteed-live slot)
  u64 nm = (u64)s1slot | ((u64)s2slot << 11)
         | ((u64)wxn << 22) | ((u64)(u32)slot_of[NIN + opn] << 25);
  ((u64*)(ws + WS_SCHED))[j] = nm;
  if (j == 0) {
    wl[1026] = (u32)slot_of[NNODES - 1];
    wl[1027] = (s_next > cap || s_nlev > 254) ? 1u : 0u;
  }
}

// ---------------- weights: unify + zero-pad + transpose + XOR-swizzle into global staging ----------------
// layout: mat m base = m*16384, row n: 256B; byte within row = (k*2) ^ ((n&7)<<4)
// one-input mats (m<4): k>=64 half is ZERO (reference W_pad semantics)
__global__ __launch_bounds__(256) void k_weights(const float* __restrict__ oW,
                                                 const float* __restrict__ ob,
                                                 const float* __restrict__ tW,
                                                 const float* __restrict__ tb,
                                                 char* __restrict__ ws) {
  f16* wt = (f16*)(ws + WS_WT);
  int t = blockIdx.x * 256 + threadIdx.x;   // 64 blocks -> 16384 threads, 4 elems each
  #pragma unroll
  for (int q = 0; q < 4; ++q) {
    int e = t * 4 + q;                       // e = mat*8192 + n*128 + k
    int mat = e >> 13, n = (e >> 7) & 63, k = e & 127;
    float v;
    if (mat < 4) v = (k < 64) ? oW[mat * 4096 + k * 64 + n] : 0.f;
    else         v = tW[(mat - 4) * 8192 + k * 64 + n];
    u32 off = (u32)mat * 16384u + (u32)n * 256u + (u32)((k * 2) ^ ((n & 7) << 4));
    *(f16*)((char*)wt + off) = (f16)v;
  }
  if (blockIdx.x == 0) {
    float* bs = (float*)(ws + WS_BIAS);
    for (int q = threadIdx.x; q < 512; q += 256)
      bs[q] = (q < 256) ? ob[q] : tb[q - 256];
  }
}

// ---------------- leaves: embedding gather -> slots 0..63 (fp16, vectorized) ----------------
__global__ __launch_bounds__(256) void k_leaves(const int* __restrict__ ids,
                                                const float* __restrict__ emb,
                                                char* __restrict__ ws) {
  int p = blockIdx.x * 256 + threadIdx.x;      // 131072 (i,b) pairs
  int i = p >> 11, b = p & 2047;
  int id = ids[b * 64 + i];
  const f32x4* src = (const f32x4*)(emb + (u32)id * 64u);
  f16x8* dst = (f16x8*)(ws + WS_NODES + ((u32)i << SLAB_SH) + (u32)b * 128u);
  #pragma unroll
  for (int q = 0; q < 8; ++q) {
    f32x4 lo = src[2 * q], hi = src[2 * q + 1];
    f16x8 v = { (f16)lo.x, (f16)lo.y, (f16)lo.z, (f16)lo.w,
                (f16)hi.x, (f16)hi.y, (f16)hi.z, (f16)hi.w };
    dst[q] = v;
  }
}

// ---------------- main: 256 blocks x 8 rows, branch-free uniform ops, depth-2 pipeline ----------------
struct Slot { f16x8 a0, a1, a2, a3, w0, w1, w2, w3; f32x4 bias; u64 oaddr; };

__global__ __launch_bounds__(1024, 4) void k_main(char* __restrict__ ws) {
  extern __shared__ char lds[];
  const int tid = threadIdx.x;
  const u32* wl = (const u32*)(ws + WS_LEV);
  if (wl[1027]) return;            // uniform early-out before any barrier

  // stage W_pad (linear 16B copy of pre-swizzled global), sched, bias, levels
  {
    const f16x8* gw = (const f16x8*)(ws + WS_WT);
    f16x8* lw = (f16x8*)(lds + L_WT);
    for (int u = tid; u < 8192; u += 1024) lw[u] = gw[u];
    ((u64*)(lds + L_SCHED))[tid] = ((const u64*)(ws + WS_SCHED))[tid];
    if (tid < 512) ((float*)(lds + L_BIAS))[tid] = ((const float*)(ws + WS_BIAS))[tid];
    if (tid < 256) ((u32*)(lds + L_LEV))[tid] = wl[tid];
  }
  __syncthreads();

  const u64*   s_sched = (const u64*)(lds + L_SCHED);
  const float* s_bias  = (const float*)(lds + L_BIAS);
  const u32*   s_lev   = (const u32*)(lds + L_LEV);
  const int nlev = (int)s_lev[0];

  const int lane = tid & 63;
  const int w  = tid >> 6;          // 16 waves
  const int g  = w >> 2;            // op-group 0..3
  const int ct = w & 3;             // col-tile 0..3
  const int n0 = ct * 16;
  const int r0 = blockIdx.x * 8;    // 256 blocks x 8 batch rows
  const int lhi = lane >> 4, llo = lane & 15;
  char* nodes = ws + WS_NODES;

  // x as B-operand: col=llo -> batch row (dup llo&7), k = lhi*8+j per 32-k chunk
  const u32 a_off  = (u32)((r0 + (llo & 7)) * 128 + lhi * 16);
  // D: col=llo (batch row), rows n = n0+lhi*4+j -> 8B store, llo<8 only
  const u32 st_off = (u32)((r0 + llo) * 128 + (n0 + lhi * 4) * 2);
  const int n_me   = n0 + llo;                 // W row this lane supplies (A-operand row)
  const u32 roW    = (u32)(n_me * 256);        // 256B rows, all mats
  const u32 swz    = (u32)((n_me & 7) << 4);
  const u32 bq     = (u32)(n0 + lhi * 4);

  auto loadS = [&](Slot& S, int k, int k1) {
    int kc = k < k1 ? k : k1 - 1;              // branchless clamp
    u64 m = s_sched[kc];
    u32 i1 = (u32)m & 2047u;
    u32 i2 = ((u32)(m >> 11)) & 2047u;
    u32 wx = ((u32)(m >> 22)) & 7u;
    u32 os = ((u32)(m >> 25)) & 2047u;
    const char* b1 = nodes + ((u64)i1 << SLAB_SH) + a_off;
    S.a0 = *(const f16x8*)(b1);
    S.a1 = *(const f16x8*)(b1 + 64);
    const char* b2 = nodes + ((u64)i2 << SLAB_SH) + a_off;
    S.a2 = *(const f16x8*)(b2);
    S.a3 = *(const f16x8*)(b2 + 64);
    const char* wb = lds + (wx * 16384u + roW);
    S.w0 = *(const f16x8*)(wb + ((lhi * 16 +   0) ^ swz));
    S.w1 = *(const f16x8*)(wb + ((lhi * 16 +  64) ^ swz));
    S.w2 = *(const f16x8*)(wb + ((lhi * 16 + 128) ^ swz));
    S.w3 = *(const f16x8*)(wb + ((lhi * 16 + 192) ^ swz));
    S.bias = *(const f32x4*)(s_bias + wx * 64u + bq);
    S.oaddr = ((u64)os << SLAB_SH) + st_off;
  };

  auto computeS = [&](Slot& S) {
    f32x4 acc = S.bias;
    acc = MFMA16(S.w0, S.a0, acc);
    acc = MFMA16(S.w1, S.a1, acc);
    acc = MFMA16(S.w2, S.a2, acc);
    acc = MFMA16(S.w3, S.a3, acc);
    f16x4 r = { (f16)(acc.x > 0.f ? acc.x : 0.f), (f16)(acc.y > 0.f ? acc.y : 0.f),
                (f16)(acc.z > 0.f ? acc.z : 0.f), (f16)(acc.w > 0.f ? acc.w : 0.f) };
    if (llo < 8) *(f16x4*)(nodes + S.oaddr) = r;
  };

  for (int L = 1; L <= nlev; ++L) {
    const int k0 = (int)s_lev[L], k1 = (int)s_lev[L + 1];
    const int kb = k0 + g;
    Slot A, B;
    loadS(A, kb, k1);
    for (int k = kb; k < k1; k += 8) {
      loadS(B, k + 4, k1);
      computeS(A);
      loadS(A, k + 8, k1);
      if (k + 4 < k1) computeS(B);
    }
    __syncthreads();   // level boundary
  }
}

// ---------------- final: out[b] = nodes[slot1087][b] . final_W + final_b ----------------
__global__ __launch_bounds__(256) void k_final(const float* __restrict__ fw,
                                               const float* __restrict__ fb,
                                               const char* __restrict__ ws,
                                               float* __restrict__ out) {
  __shared__ float s_fw[64];
  int t = threadIdx.x;
  if (t < 64) s_fw[t] = fw[t];
  __syncthreads();
  int b = blockIdx.x * 256 + t;
  const u32* wl = (const u32*)(ws + WS_LEV);
  if (wl[1027]) { out[b] = 0.f; return; }
  u32 slot = wl[1026];
  const f16x8* last = (const f16x8*)(ws + WS_NODES + ((u64)slot << SLAB_SH) + (u32)b * 128u);
  float acc = fb[0];
  #pragma unroll
  for (int q = 0; q < 8; ++q) {
    f16x8 v = last[q];
    #pragma unroll
    for (int e = 0; e < 8; ++e) acc += (float)v[e] * s_fw[q * 8 + e];
  }
  out[b] = acc;
}

extern "C" void kernel_launch(void* const* d_in, const int* in_sizes, int n_in,
                              void* d_out, int out_size, void* d_ws, size_t ws_size,
                              hipStream_t stream) {
  const int*   ids = (const int*)d_in[0];
  const int*   wx  = (const int*)d_in[1];
  const int*   i1  = (const int*)d_in[2];
  const int*   i2  = (const int*)d_in[3];
  const float* emb = (const float*)d_in[4];
  const float* oW  = (const float*)d_in[5];
  const float* ob  = (const float*)d_in[6];
  const float* tW  = (const float*)d_in[7];
  const float* tb  = (const float*)d_in[8];
  const float* fw  = (const float*)d_in[9];
  const float* fb  = (const float*)d_in[10];
  char* ws = (char*)d_ws;
  float* out = (float*)d_out;

  int cap = (int)((ws_size > (size_t)WS_NODES) ? ((ws_size - WS_NODES) >> SLAB_SH) : 0);
  if (cap < 80) return;
  if (cap > 2047) cap = 2047;

  hipLaunchKernelGGL(k_sched,   dim3(1),   dim3(1024), 0, stream, wx, i1, i2, ws, cap);
  hipLaunchKernelGGL(k_weights, dim3(64),  dim3(256),  0, stream, oW, ob, tW, tb, ws);
  hipLaunchKernelGGL(k_leaves,  dim3(512), dim3(256),  0, stream, ids, emb, ws);
  hipLaunchKernelGGL(k_main,    dim3(256), dim3(1024), L_TOTAL, stream, ws);
  hipLaunchKernelGGL(k_final,   dim3(8),   dim3(256),  0, stream, fw, fb, ws, out);
}

// Round 6
// 328.510 us; speedup vs baseline: 2.7281x; 1.6394x over previous
//
#include <hip/hip_runtime.h>

// ---- problem constants ----
#define NIN 64
#define NOPS 1024
#define NB 2048
#define NNODES 1088            // NIN + NOPS
#define SLAB_SH 18             // node slot stride = 2048 rows * 128 B = 1<<18

// ---- workspace layout (bytes) ----
#define WS_SCHED 0u            // u64[1024] packed (slot-compacted) ops, sorted by (level, mat)
#define WS_LEV   8192u         // u32: [0]=nlev, [1]=slot of node 1087, [2]=err; +4096: u16 msta[2048]
#define WS_WT    16384u        // f16[8][64][128]  ([mat][n][k]), one-input mats zero-padded k>=64
#define WS_BIAS  147456u       // f32[512]
#define WS_SINK  149504u       // 64KB junk-lane store sink
#define WS_NODES 215040u       // f16[cap][2048][64] slot slabs

typedef unsigned int u32;
typedef unsigned short u16;
typedef unsigned long long u64;
typedef _Float16 f16;
typedef _Float16 f16x8 __attribute__((ext_vector_type(8)));
typedef _Float16 f16x4 __attribute__((ext_vector_type(4)));
typedef float f32x4 __attribute__((ext_vector_type(4)));

#define MFMA16(a, b, c) __builtin_amdgcn_mfma_f32_16x16x32_f16((a), (b), (c), 0, 0, 0)

// ---------------- schedule: levels + (level,mat) counting sort + liveness slot allocation ----------------
__global__ __launch_bounds__(1024) void k_sched(const int* __restrict__ wxv,
                                                const int* __restrict__ in1v,
                                                const int* __restrict__ in2v,
                                                char* __restrict__ ws, int cap) {
  __shared__ int s1[NOPS], s2[NOPS], sw[NOPS], slv[NOPS];
  __shared__ int lcnt[132];
  __shared__ int cnt2[1032];
  __shared__ u64 s_pack[NOPS];
  __shared__ int dl[NNODES], slot_of[NNODES], stk[NNODES];
  __shared__ int s_flag, s_nlev, s_top, s_next;
  const int j = threadIdx.x;
  s1[j] = in1v[j]; s2[j] = in2v[j]; sw[j] = wxv[j]; slv[j] = 1;
  if (j < 132) lcnt[j] = 0;
  if (j < 1032) cnt2[j] = 0;
  __syncthreads();
  // monotone relaxation: lvl[j] = 1 + max(lvl(parents)); one-input ops depend only on in1
  for (int it = 0; it < NOPS + 1; ++it) {
    if (j == 0) s_flag = 0;
    __syncthreads();
    int p1 = s1[j];
    int l1 = (p1 >= NIN) ? slv[p1 - NIN] : 0;
    int l2 = 0;
    if (sw[j] >= 4) { int p2 = s2[j]; l2 = (p2 >= NIN) ? slv[p2 - NIN] : 0; }
    int nl = 1 + (l1 > l2 ? l1 : l2);
    if (nl != slv[j]) { slv[j] = nl; s_flag = 1; }
    __syncthreads();
    int f = s_flag;
    __syncthreads();
    if (!f) break;
  }
  if (j == 0) s_nlev = 0;
  __syncthreads();
  atomicMax(&s_nlev, slv[j]);
  __syncthreads();
  u32* wl = (u32*)(ws + WS_LEV);
  const int nlev = s_nlev;
  if (nlev > 127) { if (j == 0) { wl[0] = 0; wl[1] = 0; wl[2] = 1; } return; }
  atomicAdd(&lcnt[slv[j]], 1);
  atomicAdd(&cnt2[slv[j] * 8 + sw[j]], 1);
  __syncthreads();
  if (j == 0) {
    int acc = 0;
    for (int L = 1; L <= nlev; ++L) { int c = lcnt[L]; lcnt[L] = acc; acc += c; }  // lcnt[L] := level base
  }
  __syncthreads();
  // per-(L,m) bases (flat prefix), read phase then write phase
  int base = -1;
  if (j >= 8 && j < (nlev + 1) * 8) {
    int L = j >> 3, mm = j & 7;
    int s = lcnt[L];
    for (int q = 0; q < mm; ++q) s += cnt2[L * 8 + q];
    base = s;
  }
  u16* msta = (u16*)(ws + WS_LEV + 4096);
  for (int t = j; t < 2048; t += 1024) msta[t] = (u16)NOPS;
  __syncthreads();
  if (base >= 0) { cnt2[j] = base; msta[j] = (u16)base; }   // cnt2 becomes the cursor
  __syncthreads();
  { int slot = atomicAdd(&cnt2[slv[j] * 8 + sw[j]], 1);
    u64 p = (u64)(u32)s1[j] | ((u64)(u32)s2[j] << 11) | ((u64)(u32)sw[j] << 22) | ((u64)(u32)j << 25);
    s_pack[slot] = p; }
  // death levels
  for (int t = j; t < NNODES; t += 1024) dl[t] = (t < NIN) ? 0 : slv[t - NIN];
  __syncthreads();
  atomicMax(&dl[s1[j]], slv[j]);
  if (sw[j] >= 4) atomicMax(&dl[s2[j]], slv[j]);
  __syncthreads();
  if (j == 0) { dl[NNODES - 1] = nlev + 1; s_top = 0; s_next = NIN; }
  if (j < NIN) slot_of[j] = j;
  __syncthreads();
  // greedy interval-coloring by level: free (dl == L-1) then allocate (slv == L)
  for (int L = 1; L <= nlev; ++L) {
    for (int t = j; t < NNODES; t += 1024)
      if (dl[t] == L - 1) { int p = atomicAdd(&s_top, 1); stk[p] = slot_of[t]; }
    __syncthreads();
    if (slv[j] == L) {
      int p = atomicSub(&s_top, 1);
      int s;
      if (p >= 1) s = stk[p - 1]; else s = atomicAdd(&s_next, 1);
      slot_of[NIN + j] = s;
    }
    __syncthreads();
    if (j == 0 && s_top < 0) s_top = 0;
    __syncthreads();
  }
  // rewrite schedule entries with slot indices
  u64 m = s_pack[j];
  int i1n = (int)(m & 2047u), i2n = (int)((m >> 11) & 2047u);
  u32 wxn = (u32)((m >> 22) & 7u), opn = (u32)((m >> 25) & 2047u);
  u32 s1slot = (u32)slot_of[i1n];
  u32 s2slot = (wxn >= 4) ? (u32)slot_of[i2n] : s1slot;   // one-input: i2:=i1 (zero W-half; live slot)
  u64 nm = (u64)s1slot | ((u64)s2slot << 11)
         | ((u64)wxn << 22) | ((u64)(u32)slot_of[NIN + opn] << 25);
  ((u64*)(ws + WS_SCHED))[j] = nm;
  if (j == 0) {
    wl[0] = (u32)nlev;
    wl[1] = (u32)slot_of[NNODES - 1];
    wl[2] = (s_next > cap) ? 1u : 0u;
  }
}

// ---------------- weights: unify + zero-pad + transpose to [mat][n][k], fp16, plain ----------------
__global__ __launch_bounds__(256) void k_weights(const float* __restrict__ oW,
                                                 const float* __restrict__ ob,
                                                 const float* __restrict__ tW,
                                                 const float* __restrict__ tb,
                                                 char* __restrict__ ws) {
  f16* wt = (f16*)(ws + WS_WT);
  int t = blockIdx.x * 256 + threadIdx.x;   // 64 blocks -> 16384 threads, 4 elems each
  #pragma unroll
  for (int q = 0; q < 4; ++q) {
    int e = t * 4 + q;                       // e = mat*8192 + n*128 + k
    int mat = e >> 13, n = (e >> 7) & 63, k = e & 127;
    float v;
    if (mat < 4) v = (k < 64) ? oW[mat * 4096 + k * 64 + n] : 0.f;
    else         v = tW[(mat - 4) * 8192 + k * 64 + n];
    wt[e] = (f16)v;
  }
  if (blockIdx.x == 0) {
    float* bs = (float*)(ws + WS_BIAS);
    for (int q = threadIdx.x; q < 512; q += 256)
      bs[q] = (q < 256) ? ob[q] : tb[q - 256];
  }
}

// ---------------- leaves: embedding gather -> slots 0..63 (fp16, vectorized) ----------------
__global__ __launch_bounds__(256) void k_leaves(const int* __restrict__ ids,
                                                const float* __restrict__ emb,
                                                char* __restrict__ ws) {
  int p = blockIdx.x * 256 + threadIdx.x;      // 131072 (i,b) pairs
  int i = p >> 11, b = p & 2047;
  int id = ids[b * 64 + i];
  const f32x4* src = (const f32x4*)(emb + (u32)id * 64u);
  f16x8* dst = (f16x8*)(ws + WS_NODES + ((u32)i << SLAB_SH) + (u32)b * 128u);
  #pragma unroll
  for (int q = 0; q < 8; ++q) {
    f32x4 lo = src[2 * q], hi = src[2 * q + 1];
    f16x8 v = { (f16)lo.x, (f16)lo.y, (f16)lo.z, (f16)lo.w,
                (f16)hi.x, (f16)hi.y, (f16)hi.z, (f16)hi.w };
    dst[q] = v;
  }
}

// ---------------- main: mat-specialized waves, W in registers, 256 blocks x 8 rows ----------------
struct SlotN { f16x8 a0, a1, a2, a3; u32 os; };

__global__ __launch_bounds__(1024, 4) void k_main(char* __restrict__ ws) {
  __shared__ u64 s_sched[NOPS];   // 8 KB
  __shared__ u16 s_msta[2048];    // 4 KB
  const int tid = threadIdx.x;
  const u32* wl = (const u32*)(ws + WS_LEV);
  if (wl[2]) return;               // uniform early-out before any barrier
  s_sched[tid] = ((const u64*)(ws + WS_SCHED))[tid];
  ((u32*)s_msta)[tid] = ((const u32*)(ws + WS_LEV + 4096))[tid & 1023];
  const int nlev = (int)wl[0];

  const int lane = tid & 63;
  const int w   = tid >> 6;        // 16 waves
  const int m   = w & 7;           // owned weight matrix
  const int nh  = w >> 3;          // column half: cols nh*32 .. nh*32+31
  const int lhi = lane >> 4, llo = lane & 15;
  const int r0  = blockIdx.x * 8;  // 256 blocks x 8 batch rows
  char* nodes = ws + WS_NODES;

  // W cache: full (32 cols x 128 k) slice of mat m in 8 x f16x8 = 32 VGPRs. Loaded once.
  const f16* wp = (const f16*)(ws + WS_WT) + m * 8192 + (nh * 32 + llo) * 128 + lhi * 8;
  const f16x8 W00 = *(const f16x8*)(wp +        0), W01 = *(const f16x8*)(wp +       32),
              W02 = *(const f16x8*)(wp +       64), W03 = *(const f16x8*)(wp +       96),
              W10 = *(const f16x8*)(wp + 2048 + 0), W11 = *(const f16x8*)(wp + 2048 + 32),
              W12 = *(const f16x8*)(wp + 2048 + 64), W13 = *(const f16x8*)(wp + 2048 + 96);
  const float* bsp = (const float*)(ws + WS_BIAS) + m * 64 + nh * 32 + lhi * 4;
  const f32x4 B0 = *(const f32x4*)(bsp), B1 = *(const f32x4*)(bsp + 16);
  __syncthreads();

  // x as B-operand: col=llo -> batch row (dup llo&7), k = lhi*8+e per 32-k chunk
  const u32 a_off  = (u32)((r0 + (llo & 7)) * 128 + lhi * 16);
  // D: col=llo (batch row), rows n = nh*32 + {0,16} + lhi*4+j -> two 8B stores
  const u32 st_off = (u32)((r0 + llo) * 128 + (nh * 32 + lhi * 4) * 2);
  char* sinkp = ws + WS_SINK + (u32)blockIdx.x * 256u + (u32)lhi * 64u;

  auto loadS = [&](SlotN& S, int k) {
    u64 md = s_sched[k];
    u32 i1 = (u32)md & 2047u;
    u32 i2 = ((u32)(md >> 11)) & 2047u;
    S.os   = ((u32)(md >> 25)) & 2047u;
    const char* b1 = nodes + ((u64)i1 << SLAB_SH) + a_off;
    S.a0 = *(const f16x8*)(b1);        // k 0..31   (in1 lo)
    S.a1 = *(const f16x8*)(b1 + 64);   // k 32..63  (in1 hi)
    const char* b2 = nodes + ((u64)i2 << SLAB_SH) + a_off;
    S.a2 = *(const f16x8*)(b2);        // k 64..95  (in2 lo)
    S.a3 = *(const f16x8*)(b2 + 64);   // k 96..127 (in2 hi)
  };

  auto computeS = [&](SlotN& S) {
    f32x4 c0 = B0, c1 = B1;
    c0 = MFMA16(W00, S.a0, c0); c0 = MFMA16(W01, S.a1, c0);
    c0 = MFMA16(W02, S.a2, c0); c0 = MFMA16(W03, S.a3, c0);
    c1 = MFMA16(W10, S.a0, c1); c1 = MFMA16(W11, S.a1, c1);
    c1 = MFMA16(W12, S.a2, c1); c1 = MFMA16(W13, S.a3, c1);
    f16x4 r0v = { (f16)(c0.x > 0.f ? c0.x : 0.f), (f16)(c0.y > 0.f ? c0.y : 0.f),
                  (f16)(c0.z > 0.f ? c0.z : 0.f), (f16)(c0.w > 0.f ? c0.w : 0.f) };
    f16x4 r1v = { (f16)(c1.x > 0.f ? c1.x : 0.f), (f16)(c1.y > 0.f ? c1.y : 0.f),
                  (f16)(c1.z > 0.f ? c1.z : 0.f), (f16)(c1.w > 0.f ? c1.w : 0.f) };
    char* st = (llo < 8) ? (nodes + ((u64)S.os << SLAB_SH) + st_off) : sinkp;
    *(f16x4*)(st)      = r0v;
    *(f16x4*)(st + 32) = r1v;
  };

  for (int L = 1; L <= nlev; ++L) {
    int k0 = (int)s_msta[L * 8 + m];
    int k1 = (int)s_msta[L * 8 + m + 1];
    k0 = __builtin_amdgcn_readfirstlane(k0);
    k1 = __builtin_amdgcn_readfirstlane(k1);
    if (k0 < k1) {                    // wave-uniform; empty (level,mat) skips to barrier
      SlotN A, B;
      loadS(A, k0);
      for (int k = k0; k < k1; k += 2) {
        int kn1 = (k + 1 < k1) ? k + 1 : k1 - 1;
        int kn2 = (k + 2 < k1) ? k + 2 : k1 - 1;
        loadS(B, kn1);
        computeS(A);                  // odd tails recompute last op: idempotent rewrite
        loadS(A, kn2);
        computeS(B);
      }
    }
    __syncthreads();   // level boundary
  }
}

// ---------------- final: out[b] = nodes[slot1087][b] . final_W + final_b ----------------
__global__ __launch_bounds__(256) void k_final(const float* __restrict__ fw,
                                               const float* __restrict__ fb,
                                               const char* __restrict__ ws,
                                               float* __restrict__ out) {
  __shared__ float s_fw[64];
  int t = threadIdx.x;
  if (t < 64) s_fw[t] = fw[t];
  __syncthreads();
  int b = blockIdx.x * 256 + t;
  const u32* wl = (const u32*)(ws + WS_LEV);
  if (wl[2]) { out[b] = 0.f; return; }
  u32 slot = wl[1];
  const f16x8* last = (const f16x8*)(ws + WS_NODES + ((u64)slot << SLAB_SH) + (u32)b * 128u);
  float acc = fb[0];
  #pragma unroll
  for (int q = 0; q < 8; ++q) {
    f16x8 v = last[q];
    #pragma unroll
    for (int e = 0; e < 8; ++e) acc += (float)v[e] * s_fw[q * 8 + e];
  }
  out[b] = acc;
}

extern "C" void kernel_launch(void* const* d_in, const int* in_sizes, int n_in,
                              void* d_out, int out_size, void* d_ws, size_t ws_size,
                              hipStream_t stream) {
  const int*   ids = (const int*)d_in[0];
  const int*   wx  = (const int*)d_in[1];
  const int*   i1  = (const int*)d_in[2];
  const int*   i2  = (const int*)d_in[3];
  const float* emb = (const float*)d_in[4];
  const float* oW  = (const float*)d_in[5];
  const float* ob  = (const float*)d_in[6];
  const float* tW  = (const float*)d_in[7];
  const float* tb  = (const float*)d_in[8];
  const float* fw  = (const float*)d_in[9];
  const float* fb  = (const float*)d_in[10];
  char* ws = (char*)d_ws;
  float* out = (float*)d_out;

  int cap = (int)((ws_size > (size_t)WS_NODES) ? ((ws_size - WS_NODES) >> SLAB_SH) : 0);
  if (cap < 80) return;
  if (cap > 2047) cap = 2047;

  hipLaunchKernelGGL(k_sched,   dim3(1),   dim3(1024), 0, stream, wx, i1, i2, ws, cap);
  hipLaunchKernelGGL(k_weights, dim3(64),  dim3(256),  0, stream, oW, ob, tW, tb, ws);
  hipLaunchKernelGGL(k_leaves,  dim3(512), dim3(256),  0, stream, ids, emb, ws);
  hipLaunchKernelGGL(k_main,    dim3(256), dim3(1024), 0, stream, ws);
  hipLaunchKernelGGL(k_final,   dim3(8),   dim3(256),  0, stream, fw, fb, ws, out);
}

// Round 7
// 240.505 us; speedup vs baseline: 3.7264x; 1.3659x over previous
//
#include <hip/hip_runtime.h>

// ---- problem constants ----
#define NIN 64
#define NOPS 1024
#define NB 2048
#define NNODES 1088            // NIN + NOPS
#define SLAB_SH 18             // node slot stride = 2048 rows * 128 B = 1<<18

// ---- workspace layout (bytes) ----
#define WS_SCHED 0u            // u64[1024] packed ops, sorted by (level, mat)
#define WS_LEV   8192u         // u32: [0]=nlev, [1]=slot of node 1087, [2]=err; +4096: u16 msta[2048]
#define WS_WT    16384u        // f16[8][64][128]  ([mat][n][k]), one-input mats zero-padded k>=64
#define WS_BIAS  147456u       // f32[512]
#define WS_NODES 163840u       // f16[cap][2048][64] slot slabs

// ---- k_main dynamic LDS layout (bytes) ----
#define LM_LINES 0u            // 2 levels x 64 lines x 1KB = 131072 (8 rows x 64 cols fp16, swizzled)
#define LM_SCHED 131072u       // u64[1024] = 8KB
#define LM_MSTA  139264u       // u16[2048] = 4KB
#define LM_TOTAL 143360u

typedef unsigned int u32;
typedef unsigned short u16;
typedef unsigned long long u64;
typedef _Float16 f16;
typedef _Float16 f16x8 __attribute__((ext_vector_type(8)));
typedef _Float16 f16x4 __attribute__((ext_vector_type(4)));
typedef float f32x4 __attribute__((ext_vector_type(4)));

#define MFMA16(a, b, c) __builtin_amdgcn_mfma_f32_16x16x32_f16((a), (b), (c), 0, 0, 0)

// sched word bits:
//  0-10 slot1 | 11-21 slot2 | 22-24 wx | 25-35 outslot
//  36-42 pos1, 43 fresh1 | 44-50 pos2, 51 fresh2 | 52-58 outpos, 59 ldsout | 60 globalout

// ---------------- schedule: levels + (level,mat) sort + liveness slots + LDS-edge marking ----------------
__global__ __launch_bounds__(1024) void k_sched(const int* __restrict__ wxv,
                                                const int* __restrict__ in1v,
                                                const int* __restrict__ in2v,
                                                char* __restrict__ ws, int cap) {
  __shared__ int s1[NOPS], s2[NOPS], sw[NOPS], slv[NOPS];
  __shared__ int lcnt[132];
  __shared__ int cnt2[1032];
  __shared__ u64 s_pack[NOPS];
  __shared__ int dl[NNODES], slot_of[NNODES], stk[NNODES];
  __shared__ int opPos[NOPS];
  __shared__ unsigned char needG[NOPS];
  __shared__ int s_flag, s_nlev, s_top, s_next;
  const int j = threadIdx.x;
  s1[j] = in1v[j]; s2[j] = in2v[j]; sw[j] = wxv[j]; slv[j] = 1;
  needG[j] = 0;
  if (j < 132) lcnt[j] = 0;
  if (j < 1032) cnt2[j] = 0;
  __syncthreads();
  // monotone relaxation: lvl[j] = 1 + max(lvl(parents)); one-input ops depend only on in1
  for (int it = 0; it < NOPS + 1; ++it) {
    if (j == 0) s_flag = 0;
    __syncthreads();
    int p1 = s1[j];
    int l1 = (p1 >= NIN) ? slv[p1 - NIN] : 0;
    int l2 = 0;
    if (sw[j] >= 4) { int p2 = s2[j]; l2 = (p2 >= NIN) ? slv[p2 - NIN] : 0; }
    int nl = 1 + (l1 > l2 ? l1 : l2);
    if (nl != slv[j]) { slv[j] = nl; s_flag = 1; }
    __syncthreads();
    int f = s_flag;
    __syncthreads();
    if (!f) break;
  }
  if (j == 0) s_nlev = 0;
  __syncthreads();
  atomicMax(&s_nlev, slv[j]);
  __syncthreads();
  u32* wl = (u32*)(ws + WS_LEV);
  const int nlev = s_nlev;
  if (nlev > 127) { if (j == 0) { wl[0] = 0; wl[1] = 0; wl[2] = 1; } return; }
  atomicAdd(&lcnt[slv[j]], 1);
  atomicAdd(&cnt2[slv[j] * 8 + sw[j]], 1);
  __syncthreads();
  if (j == 0) {
    int acc = 0;
    for (int L = 1; L <= nlev; ++L) { int c = lcnt[L]; lcnt[L] = acc; acc += c; }  // lcnt[L] := level base
  }
  __syncthreads();
  int base = -1;
  if (j >= 8 && j < (nlev + 1) * 8) {
    int L = j >> 3, mm = j & 7;
    int s = lcnt[L];
    for (int q = 0; q < mm; ++q) s += cnt2[L * 8 + q];
    base = s;
  }
  u16* msta = (u16*)(ws + WS_LEV + 4096);
  for (int t = j; t < 2048; t += 1024) msta[t] = (u16)NOPS;
  __syncthreads();
  if (base >= 0) { cnt2[j] = base; msta[j] = (u16)base; }   // cnt2 becomes the cursor
  __syncthreads();
  { int slot = atomicAdd(&cnt2[slv[j] * 8 + sw[j]], 1);
    u64 p = (u64)(u32)s1[j] | ((u64)(u32)s2[j] << 11) | ((u64)(u32)sw[j] << 22) | ((u64)(u32)j << 25);
    s_pack[slot] = p;
    opPos[j] = slot - lcnt[slv[j]]; }                       // position within level
  __syncthreads();
  // mark producers that need a global copy (consumer edge not LDS-servable)
  if (j == NOPS - 1) needG[j] = 1;                          // final node 1087
  { int L = slv[j];
    int i1n = s1[j];
    if (i1n >= NIN) { int p = i1n - NIN; if (!(slv[p] == L - 1 && opPos[p] < 64)) needG[p] = 1; }
    else { /* leaf: global by k_leaves */ }
    if (sw[j] >= 4) {
      int i2n = s2[j];
      if (i2n >= NIN) { int p = i2n - NIN; if (!(slv[p] == L - 1 && opPos[p] < 64)) needG[p] = 1; }
    } }
  // death levels
  for (int t = j; t < NNODES; t += 1024) dl[t] = (t < NIN) ? 0 : slv[t - NIN];
  __syncthreads();
  atomicMax(&dl[s1[j]], slv[j]);
  if (sw[j] >= 4) atomicMax(&dl[s2[j]], slv[j]);
  __syncthreads();
  if (j == 0) { dl[NNODES - 1] = nlev + 1; s_top = 0; s_next = NIN; }
  if (j < NIN) slot_of[j] = j;
  __syncthreads();
  // greedy interval-coloring by level
  for (int L = 1; L <= nlev; ++L) {
    for (int t = j; t < NNODES; t += 1024)
      if (dl[t] == L - 1) { int p = atomicAdd(&s_top, 1); stk[p] = slot_of[t]; }
    __syncthreads();
    if (slv[j] == L) {
      int p = atomicSub(&s_top, 1);
      int s;
      if (p >= 1) s = stk[p - 1]; else s = atomicAdd(&s_next, 1);
      slot_of[NIN + j] = s;
    }
    __syncthreads();
    if (j == 0 && s_top < 0) s_top = 0;
    __syncthreads();
  }
  // final packing of sorted entry j
  {
    u64 m = s_pack[j];
    int i1n = (int)(m & 2047u), i2n = (int)((m >> 11) & 2047u);
    u32 wxn = (u32)((m >> 22) & 7u);
    int opn = (int)((m >> 25) & 2047u);
    int Lop = slv[opn];
    int two = (wxn >= 4);
    if (!two) i2n = i1n;
    u32 f1 = 0, p1 = 0, f2 = 0, p2 = 0;
    if (i1n >= NIN) { int p = i1n - NIN;
      if (slv[p] == Lop - 1 && opPos[p] < 64) { f1 = 1; p1 = (u32)opPos[p]; } }
    if (i2n >= NIN) { int p = i2n - NIN;
      if (slv[p] == Lop - 1 && opPos[p] < 64) { f2 = 1; p2 = (u32)opPos[p]; } }
    u32 op_pos = (u32)opPos[opn];
    u32 ldsout = (op_pos < 64) ? 1u : 0u;
    u32 gout   = needG[opn] ? 1u : 0u;
    u32 s1slot = (u32)slot_of[i1n];
    u32 s2slot = (u32)slot_of[i2n];
    u64 nm = (u64)s1slot | ((u64)s2slot << 11) | ((u64)wxn << 22)
           | ((u64)(u32)slot_of[NIN + opn] << 25)
           | ((u64)p1 << 36) | ((u64)f1 << 43)
           | ((u64)p2 << 44) | ((u64)f2 << 51)
           | ((u64)(op_pos & 63u) << 52) | ((u64)ldsout << 59)
           | ((u64)gout << 60);
    ((u64*)(ws + WS_SCHED))[j] = nm;
  }
  if (j == 0) {
    wl[0] = (u32)nlev;
    wl[1] = (u32)slot_of[NNODES - 1];
    wl[2] = (s_next > cap) ? 1u : 0u;
  }
}

// ---------------- weights: unify + zero-pad + transpose to [mat][n][k], fp16 ----------------
__global__ __launch_bounds__(256) void k_weights(const float* __restrict__ oW,
                                                 const float* __restrict__ ob,
                                                 const float* __restrict__ tW,
                                                 const float* __restrict__ tb,
                                                 char* __restrict__ ws) {
  f16* wt = (f16*)(ws + WS_WT);
  int t = blockIdx.x * 256 + threadIdx.x;
  #pragma unroll
  for (int q = 0; q < 4; ++q) {
    int e = t * 4 + q;                       // e = mat*8192 + n*128 + k
    int mat = e >> 13, n = (e >> 7) & 63, k = e & 127;
    float v;
    if (mat < 4) v = (k < 64) ? oW[mat * 4096 + k * 64 + n] : 0.f;
    else         v = tW[(mat - 4) * 8192 + k * 64 + n];
    wt[e] = (f16)v;
  }
  if (blockIdx.x == 0) {
    float* bs = (float*)(ws + WS_BIAS);
    for (int q = threadIdx.x; q < 512; q += 256)
      bs[q] = (q < 256) ? ob[q] : tb[q - 256];
  }
}

// ---------------- leaves: embedding gather -> slots 0..63 (fp16, vectorized) ----------------
__global__ __launch_bounds__(256) void k_leaves(const int* __restrict__ ids,
                                                const float* __restrict__ emb,
                                                char* __restrict__ ws) {
  int p = blockIdx.x * 256 + threadIdx.x;      // 131072 (i,b) pairs
  int i = p >> 11, b = p & 2047;
  int id = ids[b * 64 + i];
  const f32x4* src = (const f32x4*)(emb + (u32)id * 64u);
  f16x8* dst = (f16x8*)(ws + WS_NODES + ((u32)i << SLAB_SH) + (u32)b * 128u);
  #pragma unroll
  for (int q = 0; q < 8; ++q) {
    f32x4 lo = src[2 * q], hi = src[2 * q + 1];
    f16x8 v = { (f16)lo.x, (f16)lo.y, (f16)lo.z, (f16)lo.w,
                (f16)hi.x, (f16)hi.y, (f16)hi.z, (f16)hi.w };
    dst[q] = v;
  }
}

// ---------------- main: mat-specialized waves, W in regs, LDS level-cache for fresh edges ----------------
struct SlotN { f16x8 a0, a1, a2, a3; u64 md; };

__global__ __launch_bounds__(1024, 4) void k_main(char* __restrict__ ws) {
  extern __shared__ char lds[];
  const int tid = threadIdx.x;
  const u32* wl = (const u32*)(ws + WS_LEV);
  if (wl[2]) return;               // uniform early-out before any barrier
  ((u64*)(lds + LM_SCHED))[tid] = ((const u64*)(ws + WS_SCHED))[tid];
  ((u32*)(lds + LM_MSTA))[tid] = ((const u32*)(ws + WS_LEV + 4096))[tid];
  const int nlev = (int)wl[0];

  const int lane = tid & 63;
  const int w   = tid >> 6;        // 16 waves
  const int m   = w & 7;           // owned weight matrix
  const int nh  = w >> 3;          // column half
  const int lhi = lane >> 4, llo = lane & 15;
  const int r0  = blockIdx.x * 8;  // 256 blocks x 8 batch rows
  char* nodes = ws + WS_NODES;

  // W cache: (32 cols x 128 k) slice of mat m, 32 VGPRs, loaded once
  const f16* wp = (const f16*)(ws + WS_WT) + m * 8192 + (nh * 32 + llo) * 128 + lhi * 8;
  const f16x8 W00 = *(const f16x8*)(wp +        0), W01 = *(const f16x8*)(wp +       32),
              W02 = *(const f16x8*)(wp +       64), W03 = *(const f16x8*)(wp +       96),
              W10 = *(const f16x8*)(wp + 2048 + 0), W11 = *(const f16x8*)(wp + 2048 + 32),
              W12 = *(const f16x8*)(wp + 2048 + 64), W13 = *(const f16x8*)(wp + 2048 + 96);
  const float* bsp = (const float*)(ws + WS_BIAS) + m * 64 + nh * 32 + lhi * 4;
  const f32x4 B0 = *(const f32x4*)(bsp), B1 = *(const f32x4*)(bsp + 16);
  __syncthreads();

  const u64* s_sched = (const u64*)(lds + LM_SCHED);
  const u16* s_msta  = (const u16*)(lds + LM_MSTA);

  // global A: col=llo -> batch row (dup llo&7), k chunks at lhi*16 (+64)
  const u32 a_off  = (u32)((r0 + (llo & 7)) * 128 + lhi * 16);
  // global D: col=llo, rows n = nh*32 + {0,16} + lhi*4+j
  const u32 st_off = (u32)((r0 + llo) * 128 + (nh * 32 + lhi * 4) * 2);
  // LDS line (1KB = 8 rows x 128B, swizzled byte^=(row&7)<<4)
  const u32 swr    = (u32)((llo & 7) << 4);
  const u32 aL0    = (u32)((llo & 7) * 128 + ((lhi * 16)      ^ swr));
  const u32 aL1    = (u32)((llo & 7) * 128 + ((lhi * 16 + 64) ^ swr));
  const u32 stL0   = (u32)(llo * 128 + ((nh * 64 +      lhi * 8) ^ swr));
  const u32 stL1   = (u32)(llo * 128 + ((nh * 64 + 32 + lhi * 8) ^ swr));

  auto loadS = [&](SlotN& S, int k, u32 rb) {
    u64 md = s_sched[k];
    S.md = md;
    u32 i1 = (u32)md & 2047u;
    u32 i2 = ((u32)(md >> 11)) & 2047u;
    if ((md >> 43) & 1) {
      const char* l1 = lds + rb + (((u32)(md >> 36) & 127u) << 10);
      S.a0 = *(const f16x8*)(l1 + aL0);
      S.a1 = *(const f16x8*)(l1 + aL1);
    } else {
      const char* b1 = nodes + ((u64)i1 << SLAB_SH) + a_off;
      S.a0 = *(const f16x8*)(b1);
      S.a1 = *(const f16x8*)(b1 + 64);
    }
    if ((md >> 51) & 1) {
      const char* l2 = lds + rb + (((u32)(md >> 44) & 127u) << 10);
      S.a2 = *(const f16x8*)(l2 + aL0);
      S.a3 = *(const f16x8*)(l2 + aL1);
    } else {
      const char* b2 = nodes + ((u64)i2 << SLAB_SH) + a_off;
      S.a2 = *(const f16x8*)(b2);
      S.a3 = *(const f16x8*)(b2 + 64);
    }
  };

  auto computeS = [&](SlotN& S, u32 wb) {
    f32x4 c0 = B0, c1 = B1;
    c0 = MFMA16(W00, S.a0, c0); c0 = MFMA16(W01, S.a1, c0);
    c0 = MFMA16(W02, S.a2, c0); c0 = MFMA16(W03, S.a3, c0);
    c1 = MFMA16(W10, S.a0, c1); c1 = MFMA16(W11, S.a1, c1);
    c1 = MFMA16(W12, S.a2, c1); c1 = MFMA16(W13, S.a3, c1);
    f16x4 r0v = { (f16)(c0.x > 0.f ? c0.x : 0.f), (f16)(c0.y > 0.f ? c0.y : 0.f),
                  (f16)(c0.z > 0.f ? c0.z : 0.f), (f16)(c0.w > 0.f ? c0.w : 0.f) };
    f16x4 r1v = { (f16)(c1.x > 0.f ? c1.x : 0.f), (f16)(c1.y > 0.f ? c1.y : 0.f),
                  (f16)(c1.z > 0.f ? c1.z : 0.f), (f16)(c1.w > 0.f ? c1.w : 0.f) };
    u64 md = S.md;
    if (llo < 8) {
      if ((md >> 59) & 1) {
        char* lp = lds + wb + (((u32)(md >> 52) & 127u) << 10);
        *(f16x4*)(lp + stL0) = r0v;
        *(f16x4*)(lp + stL1) = r1v;
      }
      if ((md >> 60) & 1) {
        char* st = nodes + (((u64)((md >> 25) & 2047u)) << SLAB_SH) + st_off;
        *(f16x4*)(st)      = r0v;
        *(f16x4*)(st + 32) = r1v;
      }
    }
  };

  for (int L = 1; L <= nlev; ++L) {
    const u32 rb = (u32)(((L - 1) & 1) << 16);   // read buffer (prev level)
    const u32 wb = (u32)((L & 1) << 16);         // write buffer (this level)
    int k0 = (int)s_msta[L * 8 + m];
    int k1 = (int)s_msta[L * 8 + m + 1];
    k0 = __builtin_amdgcn_readfirstlane(k0);
    k1 = __builtin_amdgcn_readfirstlane(k1);
    if (k0 < k1) {
      SlotN A, B;
      loadS(A, k0, rb);
      for (int k = k0; k < k1; k += 2) {
        int kn1 = (k + 1 < k1) ? k + 1 : k1 - 1;
        int kn2 = (k + 2 < k1) ? k + 2 : k1 - 1;
        loadS(B, kn1, rb);
        computeS(A, wb);                  // tails recompute last op: idempotent
        loadS(A, kn2, rb);
        computeS(B, wb);
      }
    }
    __syncthreads();   // level boundary: orders LDS lines + global RAW
  }
}

// ---------------- final: out[b] = nodes[slot1087][b] . final_W + final_b ----------------
__global__ __launch_bounds__(256) void k_final(const float* __restrict__ fw,
                                               const float* __restrict__ fb,
                                               const char* __restrict__ ws,
                                               float* __restrict__ out) {
  __shared__ float s_fw[64];
  int t = threadIdx.x;
  if (t < 64) s_fw[t] = fw[t];
  __syncthreads();
  int b = blockIdx.x * 256 + t;
  const u32* wl = (const u32*)(ws + WS_LEV);
  if (wl[2]) { out[b] = 0.f; return; }
  u32 slot = wl[1];
  const f16x8* last = (const f16x8*)(ws + WS_NODES + ((u64)slot << SLAB_SH) + (u32)b * 128u);
  float acc = fb[0];
  #pragma unroll
  for (int q = 0; q < 8; ++q) {
    f16x8 v = last[q];
    #pragma unroll
    for (int e = 0; e < 8; ++e) acc += (float)v[e] * s_fw[q * 8 + e];
  }
  out[b] = acc;
}

extern "C" void kernel_launch(void* const* d_in, const int* in_sizes, int n_in,
                              void* d_out, int out_size, void* d_ws, size_t ws_size,
                              hipStream_t stream) {
  const int*   ids = (const int*)d_in[0];
  const int*   wx  = (const int*)d_in[1];
  const int*   i1  = (const int*)d_in[2];
  const int*   i2  = (const int*)d_in[3];
  const float* emb = (const float*)d_in[4];
  const float* oW  = (const float*)d_in[5];
  const float* ob  = (const float*)d_in[6];
  const float* tW  = (const float*)d_in[7];
  const float* tb  = (const float*)d_in[8];
  const float* fw  = (const float*)d_in[9];
  const float* fb  = (const float*)d_in[10];
  char* ws = (char*)d_ws;
  float* out = (float*)d_out;

  int cap = (int)((ws_size > (size_t)WS_NODES) ? ((ws_size - WS_NODES) >> SLAB_SH) : 0);
  if (cap < 80) return;
  if (cap > 2047) cap = 2047;

  hipLaunchKernelGGL(k_sched,   dim3(1),   dim3(1024), 0, stream, wx, i1, i2, ws, cap);
  hipLaunchKernelGGL(k_weights, dim3(64),  dim3(256),  0, stream, oW, ob, tW, tb, ws);
  hipLaunchKernelGGL(k_leaves,  dim3(512), dim3(256),  0, stream, ids, emb, ws);
  hipLaunchKernelGGL(k_main,    dim3(256), dim3(1024), LM_TOTAL, stream, ws);
  hipLaunchKernelGGL(k_final,   dim3(8),   dim3(256),  0, stream, fw, fb, ws, out);
}

// Round 8
// 227.569 us; speedup vs baseline: 3.9382x; 1.0568x over previous
//
#include <hip/hip_runtime.h>

// ---- problem constants ----
#define NIN 64
#define NOPS 1024
#define NB 2048
#define NNODES 1088            // NIN + NOPS
#define SLAB_SH 18             // node slot stride = 2048 rows * 128 B = 1<<18

// ---- workspace layout (bytes) ----
#define WS_SCHED 0u            // u64[1024] packed ops, sorted by (level, mat)
#define WS_LEV   8192u         // u32: [0]=nlev, [1]=slot of node 1087, [2]=err; +4096: u16 msta[2048]
#define WS_WT    16384u        // f16[8][64][128]  ([mat][n][k]), one-input mats zero-padded k>=64
#define WS_BIAS  147456u       // f32[512]
#define WS_NODES 163840u       // f16[cap][2048][64] slot slabs

// ---- k_main dynamic LDS layout (bytes) ----
#define LM_LINES 0u            // 2 levels x 64 lines x 1KB = 131072 (8 rows x 64 cols fp16, swizzled)
#define LM_SCHED 131072u       // u64[1024] = 8KB
#define LM_MSTA  139264u       // u16[2048] = 4KB
#define LM_TOTAL 143360u

typedef unsigned int u32;
typedef unsigned short u16;
typedef unsigned long long u64;
typedef _Float16 f16;
typedef _Float16 f16x8 __attribute__((ext_vector_type(8)));
typedef _Float16 f16x4 __attribute__((ext_vector_type(4)));
typedef float f32x4 __attribute__((ext_vector_type(4)));

#define MFMA16(a, b, c) __builtin_amdgcn_mfma_f32_16x16x32_f16((a), (b), (c), 0, 0, 0)

// sched word bits:
//  0-10 slot1 | 11-21 slot2 | 22-24 wx | 25-35 outslot
//  36-42 pos1, 43 fresh1 | 44-50 pos2, 51 fresh2 | 52-58 outpos, 59 ldsout | 60 globalout

// ---------------- schedule: levels + (level,mat) sort + liveness slots + LDS-edge marking ----------------
__global__ __launch_bounds__(1024) void k_sched(const int* __restrict__ wxv,
                                                const int* __restrict__ in1v,
                                                const int* __restrict__ in2v,
                                                char* __restrict__ ws, int cap) {
  __shared__ int s1[NOPS], s2[NOPS], sw[NOPS], slv[NOPS];
  __shared__ int lcnt[132];
  __shared__ int cnt2[1032];
  __shared__ u64 s_pack[NOPS];
  __shared__ int dl[NNODES], slot_of[NNODES], stk[NNODES];
  __shared__ int opPos[NOPS];
  __shared__ unsigned char needG[NOPS];
  __shared__ int s_flag, s_nlev, s_top, s_next;
  const int j = threadIdx.x;
  s1[j] = in1v[j]; s2[j] = in2v[j]; sw[j] = wxv[j]; slv[j] = 1;
  needG[j] = 0;
  if (j < 132) lcnt[j] = 0;
  if (j < 1032) cnt2[j] = 0;
  __syncthreads();
  // monotone relaxation: lvl[j] = 1 + max(lvl(parents)); one-input ops depend only on in1
  for (int it = 0; it < NOPS + 1; ++it) {
    if (j == 0) s_flag = 0;
    __syncthreads();
    int p1 = s1[j];
    int l1 = (p1 >= NIN) ? slv[p1 - NIN] : 0;
    int l2 = 0;
    if (sw[j] >= 4) { int p2 = s2[j]; l2 = (p2 >= NIN) ? slv[p2 - NIN] : 0; }
    int nl = 1 + (l1 > l2 ? l1 : l2);
    if (nl != slv[j]) { slv[j] = nl; s_flag = 1; }
    __syncthreads();
    int f = s_flag;
    __syncthreads();
    if (!f) break;
  }
  if (j == 0) s_nlev = 0;
  __syncthreads();
  atomicMax(&s_nlev, slv[j]);
  __syncthreads();
  u32* wl = (u32*)(ws + WS_LEV);
  const int nlev = s_nlev;
  if (nlev > 127) { if (j == 0) { wl[0] = 0; wl[1] = 0; wl[2] = 1; } return; }
  atomicAdd(&lcnt[slv[j]], 1);
  atomicAdd(&cnt2[slv[j] * 8 + sw[j]], 1);
  __syncthreads();
  if (j == 0) {
    int acc = 0;
    for (int L = 1; L <= nlev; ++L) { int c = lcnt[L]; lcnt[L] = acc; acc += c; }  // lcnt[L] := level base
  }
  __syncthreads();
  int base = -1;
  if (j >= 8 && j < (nlev + 1) * 8) {
    int L = j >> 3, mm = j & 7;
    int s = lcnt[L];
    for (int q = 0; q < mm; ++q) s += cnt2[L * 8 + q];
    base = s;
  }
  u16* msta = (u16*)(ws + WS_LEV + 4096);
  for (int t = j; t < 2048; t += 1024) msta[t] = (u16)NOPS;
  __syncthreads();
  if (base >= 0) { cnt2[j] = base; msta[j] = (u16)base; }   // cnt2 becomes the cursor
  __syncthreads();
  { int slot = atomicAdd(&cnt2[slv[j] * 8 + sw[j]], 1);
    u64 p = (u64)(u32)s1[j] | ((u64)(u32)s2[j] << 11) | ((u64)(u32)sw[j] << 22) | ((u64)(u32)j << 25);
    s_pack[slot] = p;
    opPos[j] = slot - lcnt[slv[j]]; }                       // position within level
  __syncthreads();
  // mark producers that need a global copy (consumer edge not LDS-servable)
  if (j == NOPS - 1) needG[j] = 1;                          // final node 1087
  { int L = slv[j];
    int i1n = s1[j];
    if (i1n >= NIN) { int p = i1n - NIN; if (!(slv[p] == L - 1 && opPos[p] < 64)) needG[p] = 1; }
    if (sw[j] >= 4) {
      int i2n = s2[j];
      if (i2n >= NIN) { int p = i2n - NIN; if (!(slv[p] == L - 1 && opPos[p] < 64)) needG[p] = 1; }
    } }
  // death levels
  for (int t = j; t < NNODES; t += 1024) dl[t] = (t < NIN) ? 0 : slv[t - NIN];
  __syncthreads();
  atomicMax(&dl[s1[j]], slv[j]);
  if (sw[j] >= 4) atomicMax(&dl[s2[j]], slv[j]);
  __syncthreads();
  if (j == 0) { dl[NNODES - 1] = nlev + 1; s_top = 0; s_next = NIN; }
  if (j < NIN) slot_of[j] = j;
  __syncthreads();
  // greedy interval-coloring by level
  for (int L = 1; L <= nlev; ++L) {
    for (int t = j; t < NNODES; t += 1024)
      if (dl[t] == L - 1) { int p = atomicAdd(&s_top, 1); stk[p] = slot_of[t]; }
    __syncthreads();
    if (slv[j] == L) {
      int p = atomicSub(&s_top, 1);
      int s;
      if (p >= 1) s = stk[p - 1]; else s = atomicAdd(&s_next, 1);
      slot_of[NIN + j] = s;
    }
    __syncthreads();
    if (j == 0 && s_top < 0) s_top = 0;
    __syncthreads();
  }
  // final packing of sorted entry j
  {
    u64 m = s_pack[j];
    int i1n = (int)(m & 2047u), i2n = (int)((m >> 11) & 2047u);
    u32 wxn = (u32)((m >> 22) & 7u);
    int opn = (int)((m >> 25) & 2047u);
    int Lop = slv[opn];
    int two = (wxn >= 4);
    if (!two) i2n = i1n;
    u32 f1 = 0, p1 = 0, f2 = 0, p2 = 0;
    if (i1n >= NIN) { int p = i1n - NIN;
      if (slv[p] == Lop - 1 && opPos[p] < 64) { f1 = 1; p1 = (u32)opPos[p]; } }
    if (i2n >= NIN) { int p = i2n - NIN;
      if (slv[p] == Lop - 1 && opPos[p] < 64) { f2 = 1; p2 = (u32)opPos[p]; } }
    u32 op_pos = (u32)opPos[opn];
    u32 ldsout = (op_pos < 64) ? 1u : 0u;
    u32 gout   = needG[opn] ? 1u : 0u;
    u32 s1slot = (u32)slot_of[i1n];
    u32 s2slot = (u32)slot_of[i2n];
    u64 nm = (u64)s1slot | ((u64)s2slot << 11) | ((u64)wxn << 22)
           | ((u64)(u32)slot_of[NIN + opn] << 25)
           | ((u64)p1 << 36) | ((u64)f1 << 43)
           | ((u64)p2 << 44) | ((u64)f2 << 51)
           | ((u64)(op_pos & 63u) << 52) | ((u64)ldsout << 59)
           | ((u64)gout << 60);
    ((u64*)(ws + WS_SCHED))[j] = nm;
  }
  if (j == 0) {
    wl[0] = (u32)nlev;
    wl[1] = (u32)slot_of[NNODES - 1];
    wl[2] = (s_next > cap) ? 1u : 0u;
  }
}

// ---------------- weights: unify + zero-pad + transpose to [mat][n][k], fp16 ----------------
__global__ __launch_bounds__(256) void k_weights(const float* __restrict__ oW,
                                                 const float* __restrict__ ob,
                                                 const float* __restrict__ tW,
                                                 const float* __restrict__ tb,
                                                 char* __restrict__ ws) {
  f16* wt = (f16*)(ws + WS_WT);
  int t = blockIdx.x * 256 + threadIdx.x;
  #pragma unroll
  for (int q = 0; q < 4; ++q) {
    int e = t * 4 + q;                       // e = mat*8192 + n*128 + k
    int mat = e >> 13, n = (e >> 7) & 63, k = e & 127;
    float v;
    if (mat < 4) v = (k < 64) ? oW[mat * 4096 + k * 64 + n] : 0.f;
    else         v = tW[(mat - 4) * 8192 + k * 64 + n];
    wt[e] = (f16)v;
  }
  if (blockIdx.x == 0) {
    float* bs = (float*)(ws + WS_BIAS);
    for (int q = threadIdx.x; q < 512; q += 256)
      bs[q] = (q < 256) ? ob[q] : tb[q - 256];
  }
}

// ---------------- leaves: embedding gather -> slots 0..63 (fp16, vectorized) ----------------
__global__ __launch_bounds__(256) void k_leaves(const int* __restrict__ ids,
                                                const float* __restrict__ emb,
                                                char* __restrict__ ws) {
  int p = blockIdx.x * 256 + threadIdx.x;      // 131072 (i,b) pairs
  int i = p >> 11, b = p & 2047;
  int id = ids[b * 64 + i];
  const f32x4* src = (const f32x4*)(emb + (u32)id * 64u);
  f16x8* dst = (f16x8*)(ws + WS_NODES + ((u32)i << SLAB_SH) + (u32)b * 128u);
  #pragma unroll
  for (int q = 0; q < 8; ++q) {
    f32x4 lo = src[2 * q], hi = src[2 * q + 1];
    f16x8 v = { (f16)lo.x, (f16)lo.y, (f16)lo.z, (f16)lo.w,
                (f16)hi.x, (f16)hi.y, (f16)hi.z, (f16)hi.w };
    dst[q] = v;
  }
}

// ---------------- main: mat-specialized waves, W in regs, LDS level-cache, depth-3 pipeline ----------------
struct SlotT { f16x8 a0, a1, a2, a3; u64 md; };
struct SlotO { f16x8 a0, a1; u64 md; };

__global__ __launch_bounds__(1024, 4) void k_main(char* __restrict__ ws) {
  extern __shared__ char lds[];
  const int tid = threadIdx.x;
  const u32* wl = (const u32*)(ws + WS_LEV);
  if (wl[2]) return;               // uniform early-out before any barrier
  ((u64*)(lds + LM_SCHED))[tid] = ((const u64*)(ws + WS_SCHED))[tid];
  ((u32*)(lds + LM_MSTA))[tid] = ((const u32*)(ws + WS_LEV + 4096))[tid];
  const int nlev = (int)wl[0];

  const int lane = tid & 63;
  const int w   = tid >> 6;        // 16 waves
  const int m   = w & 7;           // owned weight matrix (constant per wave; m<4 => one-input)
  const int nh  = w >> 3;          // column half
  const int lhi = lane >> 4, llo = lane & 15;
  const int r0  = blockIdx.x * 8;  // 256 blocks x 8 batch rows
  char* nodes = ws + WS_NODES;

  // W cache: (32 cols x 128 k) slice of mat m; one-input waves load only the k<64 half
  const f16* wp = (const f16*)(ws + WS_WT) + m * 8192 + (nh * 32 + llo) * 128 + lhi * 8;
  const f16x8 W00 = *(const f16x8*)(wp +        0), W01 = *(const f16x8*)(wp +       32),
              W10 = *(const f16x8*)(wp + 2048 + 0), W11 = *(const f16x8*)(wp + 2048 + 32);
  f16x8 W02 = {}, W03 = {}, W12 = {}, W13 = {};
  if (m >= 4) {
    W02 = *(const f16x8*)(wp +       64); W03 = *(const f16x8*)(wp +       96);
    W12 = *(const f16x8*)(wp + 2048 + 64); W13 = *(const f16x8*)(wp + 2048 + 96);
  }
  const float* bsp = (const float*)(ws + WS_BIAS) + m * 64 + nh * 32 + lhi * 4;
  const f32x4 B0 = *(const f32x4*)(bsp), B1 = *(const f32x4*)(bsp + 16);
  __syncthreads();

  const u64* s_sched = (const u64*)(lds + LM_SCHED);
  const u16* s_msta  = (const u16*)(lds + LM_MSTA);

  // global A: col=llo -> batch row (dup llo&7), k chunks at lhi*16 (+64)
  const u32 a_off  = (u32)((r0 + (llo & 7)) * 128 + lhi * 16);
  // global D: col=llo, rows n = nh*32 + {0,16} + lhi*4+j
  const u32 st_off = (u32)((r0 + llo) * 128 + (nh * 32 + lhi * 4) * 2);
  // LDS line (1KB = 8 rows x 128B, swizzled byte^=(row&7)<<4)
  const u32 swr    = (u32)((llo & 7) << 4);
  const u32 aL0    = (u32)((llo & 7) * 128 + ((lhi * 16)      ^ swr));
  const u32 aL1    = (u32)((llo & 7) * 128 + ((lhi * 16 + 64) ^ swr));
  const u32 stL0   = (u32)(llo * 128 + ((nh * 64 +      lhi * 8) ^ swr));
  const u32 stL1   = (u32)(llo * 128 + ((nh * 64 + 32 + lhi * 8) ^ swr));

  auto load1 = [&](f16x8& d0, f16x8& d1, u64 md, u32 rb) {   // operand 1
    u32 i1 = (u32)md & 2047u;
    if ((md >> 43) & 1) {
      const char* l1 = lds + rb + (((u32)(md >> 36) & 127u) << 10);
      d0 = *(const f16x8*)(l1 + aL0);
      d1 = *(const f16x8*)(l1 + aL1);
    } else {
      const char* b1 = nodes + ((u64)i1 << SLAB_SH) + a_off;
      d0 = *(const f16x8*)(b1);
      d1 = *(const f16x8*)(b1 + 64);
    }
  };
  auto load2 = [&](f16x8& d0, f16x8& d1, u64 md, u32 rb) {   // operand 2
    u32 i2 = ((u32)(md >> 11)) & 2047u;
    if ((md >> 51) & 1) {
      const char* l2 = lds + rb + (((u32)(md >> 44) & 127u) << 10);
      d0 = *(const f16x8*)(l2 + aL0);
      d1 = *(const f16x8*)(l2 + aL1);
    } else {
      const char* b2 = nodes + ((u64)i2 << SLAB_SH) + a_off;
      d0 = *(const f16x8*)(b2);
      d1 = *(const f16x8*)(b2 + 64);
    }
  };
  auto storeR = [&](u64 md, u32 wb, f32x4 c0, f32x4 c1) {
    f16x4 r0v = { (f16)(c0.x > 0.f ? c0.x : 0.f), (f16)(c0.y > 0.f ? c0.y : 0.f),
                  (f16)(c0.z > 0.f ? c0.z : 0.f), (f16)(c0.w > 0.f ? c0.w : 0.f) };
    f16x4 r1v = { (f16)(c1.x > 0.f ? c1.x : 0.f), (f16)(c1.y > 0.f ? c1.y : 0.f),
                  (f16)(c1.z > 0.f ? c1.z : 0.f), (f16)(c1.w > 0.f ? c1.w : 0.f) };
    if (llo < 8) {
      if ((md >> 59) & 1) {
        char* lp = lds + wb + (((u32)(md >> 52) & 127u) << 10);
        *(f16x4*)(lp + stL0) = r0v;
        *(f16x4*)(lp + stL1) = r1v;
      }
      if ((md >> 60) & 1) {
        char* st = nodes + (((u64)((md >> 25) & 2047u)) << SLAB_SH) + st_off;
        *(f16x4*)(st)      = r0v;
        *(f16x4*)(st + 32) = r1v;
      }
    }
  };

  auto loadT = [&](SlotT& S, int k, u32 rb) {
    u64 md = s_sched[k]; S.md = md;
    load1(S.a0, S.a1, md, rb);
    load2(S.a2, S.a3, md, rb);
  };
  auto computeT = [&](SlotT& S, u32 wb) {
    f32x4 c0 = B0, c1 = B1;
    __builtin_amdgcn_s_setprio(1);
    c0 = MFMA16(W00, S.a0, c0); c0 = MFMA16(W01, S.a1, c0);
    c0 = MFMA16(W02, S.a2, c0); c0 = MFMA16(W03, S.a3, c0);
    c1 = MFMA16(W10, S.a0, c1); c1 = MFMA16(W11, S.a1, c1);
    c1 = MFMA16(W12, S.a2, c1); c1 = MFMA16(W13, S.a3, c1);
    __builtin_amdgcn_s_setprio(0);
    storeR(S.md, wb, c0, c1);
  };
  auto loadO = [&](SlotO& S, int k, u32 rb) {
    u64 md = s_sched[k]; S.md = md;
    load1(S.a0, S.a1, md, rb);
  };
  auto computeO = [&](SlotO& S, u32 wb) {
    f32x4 c0 = B0, c1 = B1;
    __builtin_amdgcn_s_setprio(1);
    c0 = MFMA16(W00, S.a0, c0); c0 = MFMA16(W01, S.a1, c0);
    c1 = MFMA16(W10, S.a0, c1); c1 = MFMA16(W11, S.a1, c1);
    __builtin_amdgcn_s_setprio(0);
    storeR(S.md, wb, c0, c1);
  };

  for (int L = 1; L <= nlev; ++L) {
    const u32 rb = (u32)(((L - 1) & 1) << 16);   // read buffer (prev level)
    const u32 wb = (u32)((L & 1) << 16);         // write buffer (this level)
    int k0 = (int)s_msta[L * 8 + m];
    int k1 = (int)s_msta[L * 8 + m + 1];
    k0 = __builtin_amdgcn_readfirstlane(k0);
    k1 = __builtin_amdgcn_readfirstlane(k1);
    if (k0 < k1) {                    // wave-uniform
      const int ke = k1 - 1;
      if (m < 4) {                    // one-input waves: 4 MFMA, 2 loads (k>=64 W-half is zero)
        SlotO S0, S1, S2;
        loadO(S0, k0, rb);
        loadO(S1, k0 + 1 > ke ? ke : k0 + 1, rb);
        loadO(S2, k0 + 2 > ke ? ke : k0 + 2, rb);
        for (int k = k0; k < k1; k += 3) {       // clamped tail: idempotent recompute
          computeO(S0, wb); loadO(S0, k + 3 > ke ? ke : k + 3, rb);
          computeO(S1, wb); loadO(S1, k + 4 > ke ? ke : k + 4, rb);
          computeO(S2, wb); loadO(S2, k + 5 > ke ? ke : k + 5, rb);
        }
      } else {                        // two-input waves: 8 MFMA, 4 loads
        SlotT S0, S1, S2;
        loadT(S0, k0, rb);
        loadT(S1, k0 + 1 > ke ? ke : k0 + 1, rb);
        loadT(S2, k0 + 2 > ke ? ke : k0 + 2, rb);
        for (int k = k0; k < k1; k += 3) {
          computeT(S0, wb); loadT(S0, k + 3 > ke ? ke : k + 3, rb);
          computeT(S1, wb); loadT(S1, k + 4 > ke ? ke : k + 4, rb);
          computeT(S2, wb); loadT(S2, k + 5 > ke ? ke : k + 5, rb);
        }
      }
    }
    __syncthreads();   // level boundary: orders LDS lines + global RAW
  }
}

// ---------------- final: out[b] = nodes[slot1087][b] . final_W + final_b ----------------
__global__ __launch_bounds__(256) void k_final(const float* __restrict__ fw,
                                               const float* __restrict__ fb,
                                               const char* __restrict__ ws,
                                               float* __restrict__ out) {
  __shared__ float s_fw[64];
  int t = threadIdx.x;
  if (t < 64) s_fw[t] = fw[t];
  __syncthreads();
  int b = blockIdx.x * 256 + t;
  const u32* wl = (const u32*)(ws + WS_LEV);
  if (wl[2]) { out[b] = 0.f; return; }
  u32 slot = wl[1];
  const f16x8* last = (const f16x8*)(ws + WS_NODES + ((u64)slot << SLAB_SH) + (u32)b * 128u);
  float acc = fb[0];
  #pragma unroll
  for (int q = 0; q < 8; ++q) {
    f16x8 v = last[q];
    #pragma unroll
    for (int e = 0; e < 8; ++e) acc += (float)v[e] * s_fw[q * 8 + e];
  }
  out[b] = acc;
}

extern "C" void kernel_launch(void* const* d_in, const int* in_sizes, int n_in,
                              void* d_out, int out_size, void* d_ws, size_t ws_size,
                              hipStream_t stream) {
  const int*   ids = (const int*)d_in[0];
  const int*   wx  = (const int*)d_in[1];
  const int*   i1  = (const int*)d_in[2];
  const int*   i2  = (const int*)d_in[3];
  const float* emb = (const float*)d_in[4];
  const float* oW  = (const float*)d_in[5];
  const float* ob  = (const float*)d_in[6];
  const float* tW  = (const float*)d_in[7];
  const float* tb  = (const float*)d_in[8];
  const float* fw  = (const float*)d_in[9];
  const float* fb  = (const float*)d_in[10];
  char* ws = (char*)d_ws;
  float* out = (float*)d_out;

  int cap = (int)((ws_size > (size_t)WS_NODES) ? ((ws_size - WS_NODES) >> SLAB_SH) : 0);
  if (cap < 80) return;
  if (cap > 2047) cap = 2047;

  hipLaunchKernelGGL(k_sched,   dim3(1),   dim3(1024), 0, stream, wx, i1, i2, ws, cap);
  hipLaunchKernelGGL(k_weights, dim3(64),  dim3(256),  0, stream, oW, ob, tW, tb, ws);
  hipLaunchKernelGGL(k_leaves,  dim3(512), dim3(256),  0, stream, ids, emb, ws);
  hipLaunchKernelGGL(k_main,    dim3(256), dim3(1024), LM_TOTAL, stream, ws);
  hipLaunchKernelGGL(k_final,   dim3(8),   dim3(256),  0, stream, fw, fb, ws, out);
}